// Round 9
// baseline (202.571 us; speedup 1.0000x reference)
//
#include <hip/hip_runtime.h>

#define BATCH 8
#define CH    48
#define NPTS  4096
#define NBN   (BATCH*NPTS)
#define KNN   9
#define NCAND 12             // per-lane filter depth

typedef unsigned short u16;
typedef unsigned int   u32;
typedef unsigned long long u64;
typedef __bf16 bf16x8 __attribute__((ext_vector_type(8)));
typedef float  f32x4  __attribute__((ext_vector_type(4)));

__device__ __forceinline__ float bf2f(u16 v) { return __uint_as_float(((u32)v) << 16); }
__device__ __forceinline__ u16 f2bf(float f) {
  u32 u = __float_as_uint(f);
  u = (u + 0x7fffu + ((u >> 16) & 1u)) >> 16;
  return (u16)u;
}

// Shared med3 insert: insert x into sorted p0<=...<=p11 keeping smallest 12.
//   p_i' = med3(p_{i-1}, p_i, x) (i=11..1, old values), p0' = min(p0, x).
#define MED3U(d, a, b, c) \
  asm("v_med3_u32 %0, %1, %2, %3" : "=v"(d) : "v"(a), "v"(b), "v"(c))
#define INS12(p0,p1,p2,p3,p4,p5,p6,p7,p8,p9,p10,p11,x) do { \
  MED3U(p11,p10,p11,x); MED3U(p10,p9,p10,x); MED3U(p9,p8,p9,x);  \
  MED3U(p8, p7, p8, x); MED3U(p7, p6,p7, x); MED3U(p6,p5,p6,x);  \
  MED3U(p5, p4, p5, x); MED3U(p4, p3,p4, x); MED3U(p3,p2,p3,x);  \
  MED3U(p2, p1, p2, x); MED3U(p1, p0,p1, x); p0 = min(p0, x);    \
} while (0)

// async global->LDS staging: per-lane global src, wave-uniform LDS base
// (HW adds lane*16B). 16B/lane x 64 lanes = 1 KB per call.
__device__ __forceinline__ void stage_q(const u16* g, u16* l) {
  __builtin_amdgcn_global_load_lds(
      (const __attribute__((address_space(1))) void*)g,
      (__attribute__((address_space(3))) void*)l, 16, 0, 0);
}

// ======================= FAST PATH (ws >= ~45 MB) =======================
// k_prep: COALESCED-WRITE rewrite. The old version's writes were all
// node-major (192-256 B stride per lane, 16 B useful per transaction ->
// ~4x write amplification; likely the hidden 25-40 us). Now: each
// 64-thread (single-wave) block computes 64 nodes and stages all packed
// outputs in LDS (57 KB), then block-copies LDS->global as CONTIGUOUS
// streams (64-node spans of xn/xraw/A/B are contiguous by construction).
// Single wave -> LDS write/read ordering is wave-sequential (barrier ~free).
// A layout [tile16][variant(4)][lane(64)][8 bf16]; B [node][hi 64][lo 64].
__global__ __launch_bounds__(64)
void k_prep(const float* __restrict__ x, float* __restrict__ xraw,
            float* __restrict__ xn, float* __restrict__ csq,
            u16* __restrict__ Abuf, u16* __restrict__ Bbuf,
            int* __restrict__ deg) {
  __shared__ __align__(16) float xrawS[64 * 48];   // 12,288 B
  __shared__ __align__(16) float xnS[64 * 48];     // 12,288 B
  __shared__ __align__(16) u16   AS[64 * 128];     // 16,384 B
  __shared__ __align__(16) u16   BS[64 * 128];     // 16,384 B
  int tid = threadIdx.x;
  int node0 = blockIdx.x * 64;
  int node = node0 + tid;
  deg[node] = 0;
  int b = node >> 12, n = node & (NPTS - 1);
  const float* xb = x + (size_t)b * CH * NPTS;
  float f[CH];
#pragma unroll
  for (int c = 0; c < CH; ++c) f[c] = xb[(size_t)c * NPTS + n];
  float a0 = 0, a1 = 0, a2 = 0, a3 = 0;
#pragma unroll
  for (int k = 0; k < CH; k += 4) {
    a0 += f[k] * f[k]; a1 += f[k+1] * f[k+1];
    a2 += f[k+2] * f[k+2]; a3 += f[k+3] * f[k+3];
  }
  float nrm = fmaxf(sqrtf((a0 + a1) + (a2 + a3)), 1e-12f);
  float rn = 1.0f / nrm;            // one exact division; xv = f*rn
  a0 = a1 = a2 = a3 = 0;
#pragma unroll
  for (int k = 0; k < CH; k += 4) {
    float v0 = f[k]*rn, v1 = f[k+1]*rn, v2 = f[k+2]*rn, v3 = f[k+3]*rn;
    a0 += v0*v0; a1 += v1*v1; a2 += v2*v2; a3 += v3*v3;
  }
  float csqv = (a0 + a1) + (a2 + a3);
  csq[node] = csqv;                 // 4 B/lane, coalesced
  // --- stage packed outputs to LDS ---
  float4* ro = (float4*)(xrawS + tid * 48);
  float4* no = (float4*)(xnS   + tid * 48);
#pragma unroll
  for (int i = 0; i < CH / 4; ++i) {
    ro[i] = make_float4(f[4*i], f[4*i+1], f[4*i+2], f[4*i+3]);
    no[i] = make_float4(f[4*i]*rn, f[4*i+1]*rn, f[4*i+2]*rn, f[4*i+3]*rn);
  }
  uint4* Bo = (uint4*)(BS + tid * 128);
  u16* Ag = AS + (tid >> 4) * 2048 + (tid & 15) * 8;
#pragma unroll
  for (int g = 0; g < 6; ++g) {
    u32 bhw[4], blw[4], ahw[4], alw[4];
#pragma unroll
    for (int j = 0; j < 4; ++j) {
      int k = g * 8 + j * 2;
      float v0 = f[k] * rn, v1 = f[k+1] * rn;
      u16 h0 = f2bf(v0), h1 = f2bf(v1);
      u16 l0 = f2bf(v0 - bf2f(h0)), l1 = f2bf(v1 - bf2f(h1));
      bhw[j] = (u32)h0 | ((u32)h1 << 16);
      blw[j] = (u32)l0 | ((u32)l1 << 16);
      float w0 = -2.0f * v0, w1 = -2.0f * v1;
      u16 g0 = f2bf(w0), g1 = f2bf(w1);
      u16 m0 = f2bf(w0 - bf2f(g0)), m1 = f2bf(w1 - bf2f(g1));
      ahw[j] = (u32)g0 | ((u32)g1 << 16);
      alw[j] = (u32)m0 | ((u32)m1 << 16);
    }
    Bo[g]     = make_uint4(bhw[0], bhw[1], bhw[2], bhw[3]);
    Bo[8 + g] = make_uint4(blw[0], blw[1], blw[2], blw[3]);
    int v = g >> 2, q = g & 3;          // hi variant: v<2; lo at +1024
    *(uint4*)(Ag + v * 512 + q * 128)        = make_uint4(ahw[0], ahw[1], ahw[2], ahw[3]);
    *(uint4*)(Ag + 1024 + v * 512 + q * 128) = make_uint4(alw[0], alw[1], alw[2], alw[3]);
  }
  { // g=6: ch48 = csq (A) / 1.0 (B); ch49-55 zero
    u16 h = f2bf(csqv); u16 l = f2bf(csqv - bf2f(h));
    Bo[6]  = make_uint4(0x3F80u, 0, 0, 0);
    Bo[14] = make_uint4(0, 0, 0, 0);
    *(uint4*)(Ag + 512 + 2 * 128)        = make_uint4((u32)h, 0, 0, 0);
    *(uint4*)(Ag + 1024 + 512 + 2 * 128) = make_uint4((u32)l, 0, 0, 0);
  }
  { // g=7: ch56-63 zero
    uint4 z = make_uint4(0, 0, 0, 0);
    Bo[7] = z; Bo[15] = z;
    *(uint4*)(Ag + 512 + 3 * 128)        = z;
    *(uint4*)(Ag + 1024 + 512 + 3 * 128) = z;
  }
  __syncthreads();   // single wave: ~free, orders LDS ops
  // --- coalesced copy-out: all four regions contiguous for this block ---
  {
    float4* xrg = (float4*)(xraw + (size_t)node0 * CH);
    float4* xng = (float4*)(xn   + (size_t)node0 * CH);
    const float4* xrs = (const float4*)xrawS;
    const float4* xns = (const float4*)xnS;
    for (int i = tid; i < 64 * 48 / 4; i += 64) { xrg[i] = xrs[i]; xng[i] = xns[i]; }
    uint4* Agl = (uint4*)(Abuf + (size_t)(node0 >> 4) * 2048);
    const uint4* As4 = (const uint4*)AS;
    for (int i = tid; i < 64 * 128 / 8; i += 64) Agl[i] = As4[i];
    uint4* Bgl = (uint4*)(Bbuf + (size_t)node0 * 128);
    const uint4* Bs4 = (const uint4*)BS;
    for (int i = tid; i < 64 * 128 / 8; i += 64) Bgl[i] = Bs4[i];
  }
}

// k_knn_m: round-6 exact structure (QUARTERS y=4 for occupancy 48%, u32
// keys, LDS staging, 2-tile barrier periods). Round-7's halves traded
// occupancy (48->29%) for candu traffic and netted negative.
// KEY: MFMA computes csq_col - 2<x_col,x_row> in [-1-eps,3+eps]; +2.5 bias
// -> strictly positive keys, raw-bits monotone. Key u32 = (bits &
// 0xFFFFF000) | global_col(12b); exact-rescore absorbs ~1e-3 quantization.
__global__ __launch_bounds__(256, 6)
void k_knn_m(const u16* __restrict__ Abuf, const u16* __restrict__ Bbuf,
             u32* __restrict__ candu) {
  __shared__ __align__(16) u16 As[2][2][2048];   // 16 KB
  int tid = threadIdx.x;
  int lane = tid & 63;
  int wv = tid >> 6;
  int quad = lane >> 4, m16 = lane & 15;
  int panel = blockIdx.x * 4 + wv;
  int row = panel * 16 + m16;
  int b4096 = row & ~(NPTS - 1);
  int quarter = blockIdx.y;
  int ct0 = quarter * 64;

  const __bf16* Bb = (const __bf16*)Bbuf + (size_t)row * 128;
  bf16x8 bh0 = *(const bf16x8*)(Bb + quad * 8);
  bf16x8 bh1 = *(const bf16x8*)(Bb + 32 + quad * 8);
  bf16x8 bl0 = *(const bf16x8*)(Bb + 64 + quad * 8);
  bf16x8 bl1 = *(const bf16x8*)(Bb + 96 + quad * 8);

  const u16* gs = Abuf + ((size_t)(b4096 >> 4) + ct0) * 2048
                  + wv * 512 + lane * 8;

  u32 s0=~0u,s1=~0u,s2=~0u,s3=~0u,s4=~0u,s5=~0u,
      s6=~0u,s7=~0u,s8=~0u,s9=~0u,s10=~0u,s11=~0u;

  const f32x4 C25 = {2.5f, 2.5f, 2.5f, 2.5f};

#define LDA(P, S, A0,A1,A2,A3) do {                                         \
    const u16* _p = &As[P][S][lane * 8];                                    \
    A0 = *(const bf16x8*)(_p);                                              \
    A1 = *(const bf16x8*)(_p + 512);                                        \
    A2 = *(const bf16x8*)(_p + 1024);                                       \
    A3 = *(const bf16x8*)(_p + 1536);                                       \
  } while (0)
#define MFMA6(ACC, A0,A1,A2,A3) do {                                        \
    ACC = __builtin_amdgcn_mfma_f32_16x16x32_bf16(A0, bh0, C25, 0, 0, 0);   \
    ACC = __builtin_amdgcn_mfma_f32_16x16x32_bf16(A1, bh1, ACC, 0, 0, 0);   \
    ACC = __builtin_amdgcn_mfma_f32_16x16x32_bf16(A0, bl0, ACC, 0, 0, 0);   \
    ACC = __builtin_amdgcn_mfma_f32_16x16x32_bf16(A1, bl1, ACC, 0, 0, 0);   \
    ACC = __builtin_amdgcn_mfma_f32_16x16x32_bf16(A2, bh0, ACC, 0, 0, 0);   \
    ACC = __builtin_amdgcn_mfma_f32_16x16x32_bf16(A3, bh1, ACC, 0, 0, 0);   \
  } while (0)
#define FILTER(ACC, CT) do {                                                \
    u32 _colb = ((u32)(CT) << 4) | ((u32)quad << 2);                        \
    _Pragma("unroll")                                                       \
    for (int _r = 0; _r < 4; ++_r) {                                        \
      u32 _u = __float_as_uint((ACC)[_r]);                                  \
      u32 _x = (_u & 0xFFFFF000u) | (_colb | (u32)_r);                      \
      INS12(s0,s1,s2,s3,s4,s5,s6,s7,s8,s9,s10,s11, _x);                     \
    }                                                                       \
  } while (0)

  f32x4 accA, accB;
  bf16x8 a0, a1, a2, a3;

  // prologue: stage tiles 0,1 -> parity 0
  stage_q(gs,        &As[0][0][wv * 512]);
  stage_q(gs + 2048, &As[0][1][wv * 512]);
  __syncthreads();

  // period 0: tiles 0,1 from parity 0; stage tiles 2,3 -> parity 1
  LDA(0, 0, a0, a1, a2, a3);
  stage_q(gs + (size_t)2 * 2048, &As[1][0][wv * 512]);
  stage_q(gs + (size_t)3 * 2048, &As[1][1][wv * 512]);
  MFMA6(accA, a0, a1, a2, a3);
  LDA(0, 1, a0, a1, a2, a3);
  MFMA6(accB, a0, a1, a2, a3);
  FILTER(accA, ct0 + 0);
  __syncthreads();

  for (int p = 1; p < 31; ++p) {
    int par = p & 1;
    LDA(par, 0, a0, a1, a2, a3);
    stage_q(gs + (size_t)(2 * p + 2) * 2048, &As[par ^ 1][0][wv * 512]);
    stage_q(gs + (size_t)(2 * p + 3) * 2048, &As[par ^ 1][1][wv * 512]);
    MFMA6(accA, a0, a1, a2, a3);          // tile 2p
    FILTER(accB, ct0 + 2 * p - 1);        // finish tile 2p-1 (covers latency)
    LDA(par, 1, a0, a1, a2, a3);
    MFMA6(accB, a0, a1, a2, a3);          // tile 2p+1
    FILTER(accA, ct0 + 2 * p);
    __syncthreads();
  }
  // period 31 (parity 1): tiles 62,63; no stage
  LDA(1, 0, a0, a1, a2, a3);
  MFMA6(accA, a0, a1, a2, a3);
  FILTER(accB, ct0 + 61);
  LDA(1, 1, a0, a1, a2, a3);
  MFMA6(accB, a0, a1, a2, a3);
  FILTER(accA, ct0 + 62);
  FILTER(accB, ct0 + 63);
#undef LDA
#undef MFMA6
#undef FILTER

  u32* o = candu + (((size_t)row * 4 + quarter) * 4 + quad) * NCAND;
  o[0]=s0; o[1]=s1; o[2]=s2; o[3]=s3; o[4]=s4; o[5]=s5;
  o[6]=s6; o[7]=s7; o[8]=s8; o[9]=s9; o[10]=s10; o[11]=s11;
}

// k_rr: FUSED reduce+rescore. 32 rows/block (1024 blocks, XCD swizzle).
// Stage 0: block's 32 xn rows + csq staged coalesced into LDS.
// Stage 1: 4 thr/row, top-12 of 48 candidates (med3 network, uint4 loads).
// Stage 2: 1 thr/row merges 48 -> top-12 keys (written back in-place).
// Stage 3: 384 rescore tasks flat over 256 threads (exact fp32 dist).
// Stage 4: 1 thr/row exact (dist,idx) top-9 -> nn write + deg histogram.
#define RWS 32
__global__ __launch_bounds__(256)
void k_rr(const u32* __restrict__ candu, const float* __restrict__ xn,
          const float* __restrict__ csq, u16* __restrict__ nn,
          int* __restrict__ deg) {
  __shared__ __align__(16) u32 cs[RWS][48];
  __shared__ __align__(16) float xnS[RWS][52];
  __shared__ float csqS[RWS];
  __shared__ float dS[RWS][12];
  __shared__ int   iS[RWS][12];
  int tid = threadIdx.x, bi = blockIdx.x;
  int row0 = (bi & 7) * NPTS + (bi >> 3) * RWS;   // XCD swizzle (perf-only)
  int b4096 = row0 & ~(NPTS - 1);
  // stage 0: xn rows + csq
  for (int i = tid; i < RWS * 12; i += 256) {
    int ln = i / 12, f4 = i % 12;
    *(float4*)&xnS[ln][f4 * 4] =
        *(const float4*)(xn + (size_t)(row0 + ln) * CH + f4 * 4);
  }
  if (tid < RWS) csqS[tid] = csq[row0 + tid];
  // stage 1: 4 thr/row over 192 candidates (48 each)
  if (tid < RWS * 4) {
    int lr = tid >> 2, q = tid & 3;
    const uint4* src = (const uint4*)(candu + (size_t)(row0 + lr) * 192 + q * 48);
    u32 t0=~0u,t1=~0u,t2=~0u,t3=~0u,t4=~0u,t5=~0u,
        t6=~0u,t7=~0u,t8=~0u,t9=~0u,t10=~0u,t11=~0u;
#pragma unroll
    for (int s = 0; s < 12; ++s) {
      uint4 v = src[s];
      INS12(t0,t1,t2,t3,t4,t5,t6,t7,t8,t9,t10,t11, v.x);
      INS12(t0,t1,t2,t3,t4,t5,t6,t7,t8,t9,t10,t11, v.y);
      INS12(t0,t1,t2,t3,t4,t5,t6,t7,t8,t9,t10,t11, v.z);
      INS12(t0,t1,t2,t3,t4,t5,t6,t7,t8,t9,t10,t11, v.w);
    }
    u32* lw = &cs[lr][q * 12];
    lw[0]=t0; lw[1]=t1; lw[2]=t2; lw[3]=t3; lw[4]=t4; lw[5]=t5;
    lw[6]=t6; lw[7]=t7; lw[8]=t8; lw[9]=t9; lw[10]=t10; lw[11]=t11;
  }
  __syncthreads();
  // stage 2
  if (tid < RWS) {
    int lr = tid;
    u32 g0=~0u,g1=~0u,g2=~0u,g3=~0u,g4=~0u,g5=~0u,
        g6=~0u,g7=~0u,g8=~0u,g9=~0u,g10=~0u,g11=~0u;
    const uint4* ls4 = (const uint4*)&cs[lr][0];
#pragma unroll
    for (int s = 0; s < 12; ++s) {
      uint4 v = ls4[s];
      INS12(g0,g1,g2,g3,g4,g5,g6,g7,g8,g9,g10,g11, v.x);
      INS12(g0,g1,g2,g3,g4,g5,g6,g7,g8,g9,g10,g11, v.y);
      INS12(g0,g1,g2,g3,g4,g5,g6,g7,g8,g9,g10,g11, v.z);
      INS12(g0,g1,g2,g3,g4,g5,g6,g7,g8,g9,g10,g11, v.w);
    }
    u32* lw = &cs[lr][0];   // in-place: reads all done (serial in thread)
    lw[0]=g0; lw[1]=g1; lw[2]=g2; lw[3]=g3; lw[4]=g4; lw[5]=g5;
    lw[6]=g6; lw[7]=g7; lw[8]=g8; lw[9]=g9; lw[10]=g10; lw[11]=g11;
  }
  __syncthreads();
  // stage 3: rescore
  for (int task = tid; task < RWS * 12; task += 256) {
    int r = task / 12, j = task % 12;
    int c = (int)(cs[r][j] & 0xFFFu);
    const float4* cp = (const float4*)(xn + (size_t)(b4096 + c) * CH);
    const float* rf = &xnS[r][0];
    float a0 = 0, a1 = 0, a2 = 0, a3 = 0;
#pragma unroll
    for (int i = 0; i < CH / 4; ++i) {
      float4 v = cp[i];
      a0 += rf[4*i]   * v.x; a1 += rf[4*i+1] * v.y;
      a2 += rf[4*i+2] * v.z; a3 += rf[4*i+3] * v.w;
    }
    float dist = (csqS[r] + csq[b4096 + c]) - 2.0f * ((a0 + a1) + (a2 + a3));
    dS[r][j] = dist; iS[r][j] = c;
  }
  __syncthreads();
  // stage 4: exact top-9
  if (tid < RWS) {
    int lr = tid;
    int row = row0 + lr;
    float gd[KNN]; int gi[KNN];
#pragma unroll
    for (int j = 0; j < KNN; ++j) { gd[j] = 3.4e38f; gi[j] = 0x7fffffff; }
    for (int s = 0; s < NCAND; ++s) {
      float dc = dS[lr][s]; int ic = iS[lr][s];
      if (dc < gd[KNN - 1] || (dc == gd[KNN - 1] && ic < gi[KNN - 1])) {
        gd[KNN - 1] = dc; gi[KNN - 1] = ic;
#pragma unroll
        for (int k2 = KNN - 1; k2 > 0; --k2) {
          bool sw = (gd[k2] < gd[k2 - 1]) ||
                    (gd[k2] == gd[k2 - 1] && gi[k2] < gi[k2 - 1]);
          if (sw) {
            float td = gd[k2]; gd[k2] = gd[k2 - 1]; gd[k2 - 1] = td;
            int ti = gi[k2]; gi[k2] = gi[k2 - 1]; gi[k2 - 1] = ti;
          }
        }
      }
    }
    u16* o = nn + (size_t)row * KNN;
    int jmax = (row == NBN - 1) ? (KNN - 1) : KNN;   // linspace tail drop
#pragma unroll
    for (int j = 0; j < KNN; ++j) o[j] = (u16)(gi[j] & (NPTS - 1));
    for (int j = 0; j < jmax; ++j)
      atomicAdd(&deg[b4096 + (gi[j] & (NPTS - 1))], 1);
  }
}

// k_out: 32 nodes/block x 8 threads/node (6 out-channels each), 1024 blocks,
// XCD swizzle.
#define ONB 32
#define LPAD 52
__global__ __launch_bounds__(256)
void k_out_f(const float* __restrict__ xraw, const u16* __restrict__ nn,
             const int* __restrict__ deg,
             const float* __restrict__ W0, const float* __restrict__ W1,
             const float* __restrict__ bias, float* __restrict__ out) {
  __shared__ float w0[CH * CH], w1[CH * CH], bs[CH];
  __shared__ __align__(16) float fS[ONB * LPAD];
  __shared__ __align__(16) float txS[ONB * LPAD];
  __shared__ float dinvS[ONB];
  int tid = threadIdx.x;
  int bi = blockIdx.x;
  int n0 = (bi & 7) * NPTS + (bi >> 3) * ONB;   // XCD swizzle (perf-only)
  int b12 = n0 & ~(NPTS - 1);
  for (int i = tid; i < CH * CH; i += 256) { w0[i] = W0[i]; w1[i] = W1[i]; }
  if (tid < CH) bs[tid] = bias[tid];
  for (int i = tid; i < ONB * 12; i += 256) {
    int ln = i / 12, f4 = i % 12;
    *(float4*)(fS + ln * LPAD + f4 * 4) =
        *(const float4*)(xraw + (size_t)(n0 + ln) * CH + f4 * 4);
  }
  if (tid < ONB) {
    int dg = deg[n0 + tid];
    dinvS[tid] = (dg > 0) ? (1.0f / sqrtf((float)dg)) : 0.0f;
  }
  __syncthreads();

  int ln = tid >> 3, p = tid & 7;   // 8 thr/node, 6 channels each
  int node = n0 + ln;
  float dn = dinvS[ln];
  const u16* nrow = nn + (size_t)node * KNN;
  bool full = (node != NBN - 1);
  float tx[6];
#pragma unroll
  for (int i = 0; i < 6; ++i) tx[i] = 0.f;
#pragma unroll
  for (int j = 0; j < KNN; ++j) {
    if (j < KNN - 1 || full) {
      int s = nrow[j] & (NPTS - 1);
      int dgs = deg[b12 + s];
      float ds = (dgs > 0) ? (1.0f / sqrtf((float)dgs)) : 0.0f;
      float w = -(ds * dn);
      const float2* pr = (const float2*)(xraw + (size_t)(b12 + s) * CH + p * 6);
#pragma unroll
      for (int q3 = 0; q3 < 3; ++q3) {
        float2 v = pr[q3];
        tx[q3*2]   += w * v.x; tx[q3*2+1] += w * v.y;
      }
    }
  }
#pragma unroll
  for (int q3 = 0; q3 < 3; ++q3)
    *(float2*)(txS + ln * LPAD + p * 6 + q3 * 2) =
        make_float2(tx[q3*2], tx[q3*2+1]);
  __syncthreads();

  float acc[6];
#pragma unroll
  for (int i = 0; i < 6; ++i) acc[i] = bs[p * 6 + i];
  const float* fr = fS + ln * LPAD;
  const float* tr = txS + ln * LPAD;
#pragma unroll
  for (int c = 0; c < CH; ++c) {
    float fc = fr[c];
    const float* wr = w0 + c * CH + p * 6;
#pragma unroll
    for (int i = 0; i < 6; ++i) acc[i] += fc * wr[i];
  }
#pragma unroll
  for (int c = 0; c < CH; ++c) {
    float tc = tr[c];
    const float* wr = w1 + c * CH + p * 6;
#pragma unroll
    for (int i = 0; i < 6; ++i) acc[i] += tc * wr[i];
  }
  float* op = out + (size_t)node * CH + p * 6;
#pragma unroll
  for (int q3 = 0; q3 < 3; ++q3)
    *(float2*)(op + q3 * 2) = make_float2(acc[q3*2], acc[q3*2+1]);
}

// ======================= FALLBACK (round-4, proven) =======================
__global__ __launch_bounds__(256)
void k_zero(int* __restrict__ deg) { deg[blockIdx.x * 256 + threadIdx.x] = 0; }

__global__ __launch_bounds__(256)
void k_hist(const u16* __restrict__ nn, int* __restrict__ deg) {
  int node = blockIdx.x * 256 + threadIdx.x;
  int b12 = node & ~(NPTS - 1);
  int jmax = (node == NBN - 1) ? (KNN - 1) : KNN;
  for (int j = 0; j < jmax; ++j)
    atomicAdd(&deg[b12 + (nn[(size_t)node * KNN + j] & (NPTS - 1))], 1);
}

__global__ __launch_bounds__(256)
void k_dinv(const int* __restrict__ deg, float* __restrict__ dinv) {
  int i = blockIdx.x * 256 + threadIdx.x;
  int dg = deg[i];
  dinv[i] = (dg > 0) ? (1.0f / sqrtf((float)dg)) : 0.0f;
}

#define NQ    4
#define QCOLS (NPTS/NQ)
#define TCOLS 32
#define NTILES (QCOLS/TCOLS)
#define RPB   64

__global__ __launch_bounds__(256)
void k_knn_nb(const float* __restrict__ x, u16* __restrict__ nn) {
  __shared__ __align__(16) float tile[NQ * TCOLS * CH];
  __shared__ float nrmS[NQ * TCOLS];
  __shared__ float csq[NQ * TCOLS];
  int tid = threadIdx.x;
  int r0 = blockIdx.x * RPB;
  int b  = r0 >> 12;
  int q  = tid >> 6;
  int lr = tid & 63;
  int n  = (r0 + lr) & (NPTS - 1);
  const float* xb = x + (size_t)b * CH * NPTS;
  float rf[CH];
#pragma unroll
  for (int c = 0; c < CH; ++c) rf[c] = xb[(size_t)c * NPTS + n];
  float sqn;
  {
    float a0 = 0, a1 = 0, a2 = 0, a3 = 0;
#pragma unroll
    for (int k = 0; k < CH; k += 4) {
      a0 += rf[k] * rf[k]; a1 += rf[k+1] * rf[k+1];
      a2 += rf[k+2] * rf[k+2]; a3 += rf[k+3] * rf[k+3];
    }
    float nrm = fmaxf(sqrtf((a0 + a1) + (a2 + a3)), 1e-12f);
#pragma unroll
    for (int c = 0; c < CH; ++c) rf[c] = rf[c] / nrm;
    a0 = a1 = a2 = a3 = 0;
#pragma unroll
    for (int k = 0; k < CH; k += 4) {
      a0 += rf[k] * rf[k]; a1 += rf[k+1] * rf[k+1];
      a2 += rf[k+2] * rf[k+2]; a3 += rf[k+3] * rf[k+3];
    }
    sqn = (a0 + a1) + (a2 + a3);
  }
  float d[KNN]; int id[KNN];
#pragma unroll
  for (int j = 0; j < KNN; ++j) { d[j] = 3.4e38f; id[j] = 0x7fffffff; }
  for (int t = 0; t < NTILES; ++t) {
    __syncthreads();
#pragma unroll
    for (int qq = 0; qq < NQ; ++qq) {
      int colbase = qq * QCOLS + t * TCOLS;
      float* dst = tile + qq * TCOLS * CH;
#pragma unroll
      for (int it = 0; it < 6; ++it) {
        int i = it * 256 + tid;
        int c = i >> 5, p = i & 31;
        dst[p * CH + c] = xb[(size_t)c * NPTS + colbase + p];
      }
    }
    __syncthreads();
    if (tid < NQ * TCOLS) {
      const float* cp = tile + tid * CH;
      float a0 = 0, a1 = 0, a2 = 0, a3 = 0;
#pragma unroll
      for (int k = 0; k < CH; k += 4) {
        float4 v = *(const float4*)(cp + k);
        a0 += v.x * v.x; a1 += v.y * v.y; a2 += v.z * v.z; a3 += v.w * v.w;
      }
      nrmS[tid] = fmaxf(sqrtf((a0 + a1) + (a2 + a3)), 1e-12f);
    }
    __syncthreads();
    for (int i = tid; i < NQ * TCOLS * CH; i += 256)
      tile[i] = tile[i] / nrmS[i / CH];
    __syncthreads();
    if (tid < NQ * TCOLS) {
      const float* cp = tile + tid * CH;
      float a0 = 0, a1 = 0, a2 = 0, a3 = 0;
#pragma unroll
      for (int k = 0; k < CH; k += 4) {
        float4 v = *(const float4*)(cp + k);
        a0 += v.x * v.x; a1 += v.y * v.y; a2 += v.z * v.z; a3 += v.w * v.w;
      }
      csq[tid] = (a0 + a1) + (a2 + a3);
    }
    __syncthreads();
    int cbase = q * QCOLS + t * TCOLS;
    const float* tq = tile + q * TCOLS * CH;
    for (int cc = 0; cc < TCOLS; ++cc) {
      const float* cp = tq + cc * CH;
      float a0 = 0, a1 = 0, a2 = 0, a3 = 0;
#pragma unroll
      for (int k = 0; k < CH; k += 4) {
        float4 v = *(const float4*)(cp + k);
        a0 += rf[k] * v.x; a1 += rf[k+1] * v.y;
        a2 += rf[k+2] * v.z; a3 += rf[k+3] * v.w;
      }
      float dist = (sqn + csq[q * TCOLS + cc]) - 2.0f * ((a0 + a1) + (a2 + a3));
      if (dist < d[KNN - 1]) {
        d[KNN - 1] = dist; id[KNN - 1] = cbase + cc;
#pragma unroll
        for (int k2 = KNN - 1; k2 > 0; --k2) {
          if (d[k2] < d[k2 - 1]) {
            float td = d[k2]; d[k2] = d[k2 - 1]; d[k2 - 1] = td;
            int ti = id[k2]; id[k2] = id[k2 - 1]; id[k2 - 1] = ti;
          }
        }
      }
    }
  }
  __syncthreads();
  float* md = tile;
  int*   mi = (int*)(tile + 256 * KNN);
#pragma unroll
  for (int j = 0; j < KNN; ++j) { md[tid * KNN + j] = d[j]; mi[tid * KNN + j] = id[j]; }
  __syncthreads();
  if (tid < RPB) {
    float fd[KNN]; int fi[KNN];
#pragma unroll
    for (int j = 0; j < KNN; ++j) { fd[j] = 3.4e38f; fi[j] = 0x7fffffff; }
    for (int qq = 0; qq < NQ; ++qq) {
      int s = qq * RPB + tid;
      for (int j = 0; j < KNN; ++j) {
        float dc = md[s * KNN + j]; int ic = mi[s * KNN + j];
        if (dc < fd[KNN - 1]) {
          fd[KNN - 1] = dc; fi[KNN - 1] = ic;
#pragma unroll
          for (int k2 = KNN - 1; k2 > 0; --k2) {
            if (fd[k2] < fd[k2 - 1]) {
              float td = fd[k2]; fd[k2] = fd[k2 - 1]; fd[k2 - 1] = td;
              int ti = fi[k2]; fi[k2] = fi[k2 - 1]; fi[k2 - 1] = ti;
            }
          }
        }
      }
    }
    u16* o = nn + (size_t)(r0 + tid) * KNN;
#pragma unroll
    for (int j = 0; j < KNN; ++j) o[j] = (u16)(fi[j] & (NPTS - 1));
  }
}

__global__ __launch_bounds__(256)
void k_out_nb(const float* __restrict__ x, const u16* __restrict__ nn,
              const float* __restrict__ dinv,
              const float* __restrict__ W0, const float* __restrict__ W1,
              const float* __restrict__ bias, float* __restrict__ out) {
  __shared__ float w0[CH * CH], w1[CH * CH], bs[CH];
  for (int i = threadIdx.x; i < CH * CH; i += 256) { w0[i] = W0[i]; w1[i] = W1[i]; }
  if (threadIdx.x < CH) bs[threadIdx.x] = bias[threadIdx.x];
  __syncthreads();
  int node = blockIdx.x * 256 + threadIdx.x;
  int b = node >> 12, n = node & (NPTS - 1);
  const float* xb = x + (size_t)b * CH * NPTS;
  float f[CH], acc[CH], tx[CH];
#pragma unroll
  for (int c = 0; c < CH; ++c) f[c] = xb[(size_t)c * NPTS + n];
#pragma unroll
  for (int o = 0; o < CH; ++o) acc[o] = bs[o];
#pragma unroll
  for (int c = 0; c < CH; ++c) {
    float fc = f[c];
    const float* wr = w0 + c * CH;
#pragma unroll
    for (int o = 0; o < CH; ++o) acc[o] += fc * wr[o];
  }
#pragma unroll
  for (int c = 0; c < CH; ++c) tx[c] = 0.f;
  float dn = dinv[node];
  int jmax = (node == NBN - 1) ? (KNN - 1) : KNN;
  for (int j = 0; j < jmax; ++j) {
    int s = nn[(size_t)node * KNN + j] & (NPTS - 1);
    float w = -(dinv[(b << 12) + s] * dn);
#pragma unroll
    for (int c = 0; c < CH; ++c) tx[c] += w * xb[(size_t)c * NPTS + s];
  }
#pragma unroll
  for (int c = 0; c < CH; ++c) {
    float tc = tx[c];
    const float* wr = w1 + c * CH;
#pragma unroll
    for (int o = 0; o < CH; ++o) acc[o] += tc * wr[o];
  }
  float4* op = (float4*)(out + (size_t)node * CH);
#pragma unroll
  for (int i = 0; i < CH / 4; ++i)
    op[i] = make_float4(acc[4*i], acc[4*i+1], acc[4*i+2], acc[4*i+3]);
}

extern "C" void kernel_launch(void* const* d_in, const int* in_sizes, int n_in,
                              void* d_out, int out_size, void* d_ws, size_t ws_size,
                              hipStream_t stream) {
  const float* x    = (const float*)d_in[0];
  const float* W0   = (const float*)d_in[1];
  const float* W1   = (const float*)d_in[2];
  const float* bias = (const float*)d_in[3];
  float* out = (float*)d_out;
  char* w = (char*)d_ws;

  const size_t SZ_XN   = (size_t)NBN * CH * 4;            //  6,291,456
  const size_t SZ_XRAW = (size_t)NBN * CH * 4;            //  6,291,456
  const size_t SZ_CSQ  = (size_t)NBN * 4;                 //    131,072
  const size_t SZ_NN   = (size_t)NBN * KNN * 2;           //    589,824
  const size_t SZ_DEG  = (size_t)NBN * 4;                 //    131,072
  const size_t SZ_AB   = (size_t)NBN * 128 * 2;           //  8,388,608
  const size_t SZ_CU   = (size_t)NBN * 16 * NCAND * 4;    // 25,165,824 (u32, 4 quarters)
  const size_t needF = SZ_XN + SZ_XRAW + SZ_CSQ + SZ_NN + SZ_DEG
                     + 2 * SZ_AB + SZ_CU;                 // ~55.4 MB

  if (ws_size >= needF) {          // FAST path: MFMA filter + fused rr
    size_t off = 0;
    float* xn   = (float*)(w + off); off += SZ_XN;
    float* xraw = (float*)(w + off); off += SZ_XRAW;
    float* csq  = (float*)(w + off); off += SZ_CSQ;
    u16*   nn   = (u16*)  (w + off); off += SZ_NN;
    int*   deg  = (int*)  (w + off); off += SZ_DEG;
    u16*   Abuf = (u16*)  (w + off); off += SZ_AB;
    u16*   Bbuf = (u16*)  (w + off); off += SZ_AB;
    u32*   candu= (u32*)  (w + off);
    k_prep    <<<NBN / 64, 64, 0, stream>>>(x, xraw, xn, csq, Abuf, Bbuf, deg);
    k_knn_m   <<<dim3(NBN / 64, 4), 256, 0, stream>>>(Abuf, Bbuf, candu);
    k_rr      <<<NBN / RWS, 256, 0, stream>>>(candu, xn, csq, nn, deg);
    k_out_f   <<<NBN / ONB, 256, 0, stream>>>(xraw, nn, deg, W0, W1, bias, out);
  } else {                         // FALLBACK: proven round-4 path (852 KB)
    u16*   nn   = (u16*)w;
    int*   deg  = (int*)(w + SZ_NN);
    float* dinv = (float*)(w + SZ_NN + SZ_DEG);
    k_knn_nb <<<NBN / RPB, 256, 0, stream>>>(x, nn);
    k_zero   <<<NBN / 256, 256, 0, stream>>>(deg);
    k_hist   <<<NBN / 256, 256, 0, stream>>>(nn, deg);
    k_dinv   <<<NBN / 256, 256, 0, stream>>>(deg, dinv);
    k_out_nb <<<NBN / 256, 256, 0, stream>>>(x, nn, dinv, W0, W1, bias, out);
  }
}

// Round 11
// 198.888 us; speedup vs baseline: 1.0185x; 1.0185x over previous
//
#include <hip/hip_runtime.h>

#define BATCH 8
#define CH    48
#define NPTS  4096
#define NBN   (BATCH*NPTS)
#define KNN   9
#define NCAND 12             // per-lane filter depth

typedef unsigned short u16;
typedef unsigned int   u32;
typedef unsigned long long u64;
typedef __bf16 bf16x8 __attribute__((ext_vector_type(8)));
typedef float  f32x4  __attribute__((ext_vector_type(4)));

__device__ __forceinline__ float bf2f(u16 v) { return __uint_as_float(((u32)v) << 16); }
__device__ __forceinline__ u16 f2bf(float f) {
  u32 u = __float_as_uint(f);
  u = (u + 0x7fffu + ((u >> 16) & 1u)) >> 16;
  return (u16)u;
}

// Shared med3 insert: insert x into sorted p0<=...<=p11 keeping smallest 12.
//   p_i' = med3(p_{i-1}, p_i, x) (i=11..1, old values), p0' = min(p0, x).
#define MED3U(d, a, b, c) \
  asm("v_med3_u32 %0, %1, %2, %3" : "=v"(d) : "v"(a), "v"(b), "v"(c))
#define INS12(p0,p1,p2,p3,p4,p5,p6,p7,p8,p9,p10,p11,x) do { \
  MED3U(p11,p10,p11,x); MED3U(p10,p9,p10,x); MED3U(p9,p8,p9,x);  \
  MED3U(p8, p7, p8, x); MED3U(p7, p6,p7, x); MED3U(p6,p5,p6,x);  \
  MED3U(p5, p4, p5, x); MED3U(p4, p3,p4, x); MED3U(p3,p2,p3,x);  \
  MED3U(p2, p1, p2, x); MED3U(p1, p0,p1, x); p0 = min(p0, x);    \
} while (0)

// async global->LDS staging: per-lane global src, wave-uniform LDS base
// (HW adds lane*16B). 16B/lane x 64 lanes = 1 KB per call.
__device__ __forceinline__ void stage_q(const u16* g, u16* l) {
  __builtin_amdgcn_global_load_lds(
      (const __attribute__((address_space(1))) void*)g,
      (__attribute__((address_space(3))) void*)l, 16, 0, 0);
}

// ======================= FAST PATH (ws >= ~45 MB) =======================
// k_prep: LDS-staged coalesced writes (round-9 structure).
__global__ __launch_bounds__(64)
void k_prep(const float* __restrict__ x, float* __restrict__ xraw,
            float* __restrict__ xn, float* __restrict__ csq,
            u16* __restrict__ Abuf, u16* __restrict__ Bbuf,
            int* __restrict__ deg) {
  __shared__ __align__(16) float xrawS[64 * 48];   // 12,288 B
  __shared__ __align__(16) float xnS[64 * 48];     // 12,288 B
  __shared__ __align__(16) u16   AS[64 * 128];     // 16,384 B
  __shared__ __align__(16) u16   BS[64 * 128];     // 16,384 B
  int tid = threadIdx.x;
  int node0 = blockIdx.x * 64;
  int node = node0 + tid;
  deg[node] = 0;
  int b = node >> 12, n = node & (NPTS - 1);
  const float* xb = x + (size_t)b * CH * NPTS;
  float f[CH];
#pragma unroll
  for (int c = 0; c < CH; ++c) f[c] = xb[(size_t)c * NPTS + n];
  float a0 = 0, a1 = 0, a2 = 0, a3 = 0;
#pragma unroll
  for (int k = 0; k < CH; k += 4) {
    a0 += f[k] * f[k]; a1 += f[k+1] * f[k+1];
    a2 += f[k+2] * f[k+2]; a3 += f[k+3] * f[k+3];
  }
  float nrm = fmaxf(sqrtf((a0 + a1) + (a2 + a3)), 1e-12f);
  float rn = 1.0f / nrm;            // one exact division; xv = f*rn
  a0 = a1 = a2 = a3 = 0;
#pragma unroll
  for (int k = 0; k < CH; k += 4) {
    float v0 = f[k]*rn, v1 = f[k+1]*rn, v2 = f[k+2]*rn, v3 = f[k+3]*rn;
    a0 += v0*v0; a1 += v1*v1; a2 += v2*v2; a3 += v3*v3;
  }
  float csqv = (a0 + a1) + (a2 + a3);
  csq[node] = csqv;                 // 4 B/lane, coalesced
  float4* ro = (float4*)(xrawS + tid * 48);
  float4* no = (float4*)(xnS   + tid * 48);
#pragma unroll
  for (int i = 0; i < CH / 4; ++i) {
    ro[i] = make_float4(f[4*i], f[4*i+1], f[4*i+2], f[4*i+3]);
    no[i] = make_float4(f[4*i]*rn, f[4*i+1]*rn, f[4*i+2]*rn, f[4*i+3]*rn);
  }
  uint4* Bo = (uint4*)(BS + tid * 128);
  u16* Ag = AS + (tid >> 4) * 2048 + (tid & 15) * 8;
#pragma unroll
  for (int g = 0; g < 6; ++g) {
    u32 bhw[4], blw[4], ahw[4], alw[4];
#pragma unroll
    for (int j = 0; j < 4; ++j) {
      int k = g * 8 + j * 2;
      float v0 = f[k] * rn, v1 = f[k+1] * rn;
      u16 h0 = f2bf(v0), h1 = f2bf(v1);
      u16 l0 = f2bf(v0 - bf2f(h0)), l1 = f2bf(v1 - bf2f(h1));
      bhw[j] = (u32)h0 | ((u32)h1 << 16);
      blw[j] = (u32)l0 | ((u32)l1 << 16);
      float w0 = -2.0f * v0, w1 = -2.0f * v1;
      u16 g0 = f2bf(w0), g1 = f2bf(w1);
      u16 m0 = f2bf(w0 - bf2f(g0)), m1 = f2bf(w1 - bf2f(g1));
      ahw[j] = (u32)g0 | ((u32)g1 << 16);
      alw[j] = (u32)m0 | ((u32)m1 << 16);
    }
    Bo[g]     = make_uint4(bhw[0], bhw[1], bhw[2], bhw[3]);
    Bo[8 + g] = make_uint4(blw[0], blw[1], blw[2], blw[3]);
    int v = g >> 2, q = g & 3;          // hi variant: v<2; lo at +1024
    *(uint4*)(Ag + v * 512 + q * 128)        = make_uint4(ahw[0], ahw[1], ahw[2], ahw[3]);
    *(uint4*)(Ag + 1024 + v * 512 + q * 128) = make_uint4(alw[0], alw[1], alw[2], alw[3]);
  }
  { // g=6: ch48 = csq (A) / 1.0 (B); ch49-55 zero
    u16 h = f2bf(csqv); u16 l = f2bf(csqv - bf2f(h));
    Bo[6]  = make_uint4(0x3F80u, 0, 0, 0);
    Bo[14] = make_uint4(0, 0, 0, 0);
    *(uint4*)(Ag + 512 + 2 * 128)        = make_uint4((u32)h, 0, 0, 0);
    *(uint4*)(Ag + 1024 + 512 + 2 * 128) = make_uint4((u32)l, 0, 0, 0);
  }
  { // g=7: ch56-63 zero
    uint4 z = make_uint4(0, 0, 0, 0);
    Bo[7] = z; Bo[15] = z;
    *(uint4*)(Ag + 512 + 3 * 128)        = z;
    *(uint4*)(Ag + 1024 + 512 + 3 * 128) = z;
  }
  __syncthreads();   // single wave: ~free, orders LDS ops
  {
    float4* xrg = (float4*)(xraw + (size_t)node0 * CH);
    float4* xng = (float4*)(xn   + (size_t)node0 * CH);
    const float4* xrs = (const float4*)xrawS;
    const float4* xns = (const float4*)xnS;
    for (int i = tid; i < 64 * 48 / 4; i += 64) { xrg[i] = xrs[i]; xng[i] = xns[i]; }
    uint4* Agl = (uint4*)(Abuf + (size_t)(node0 >> 4) * 2048);
    const uint4* As4 = (const uint4*)AS;
    for (int i = tid; i < 64 * 128 / 8; i += 64) Agl[i] = As4[i];
    uint4* Bgl = (uint4*)(Bbuf + (size_t)node0 * 128);
    const uint4* Bs4 = (const uint4*)BS;
    for (int i = tid; i < 64 * 128 / 8; i += 64) Bgl[i] = Bs4[i];
  }
}

// k_knn_m: T4 COUNTED-VMCNT PIPELINE, race-fixed. vmcnt is PER-WAVE, and
// each wave reads quarters staged by OTHER waves -> the counted wait must
// come BEFORE the barrier so the barrier makes it block-wide. Per period:
//   stage(t+3) -> LDA(t) -> MFMA -> FILTER(t-1) -> VMC(2) -> s_barrier
// VMC(2) leaves outstanding {t+2, t+3}: this wave's stage(t+1) has landed;
// barrier => ALL waves' stage(t+1) landed => LDA(t+1) next period is safe.
// LDS slot reuse: stage(t+3) writes slot (t-1)&3, whose reads completed
// before the prior barrier. vmcnt never 0 in the main loop (T4); epilogue
// tapers 1 -> 0. ~2 periods (~300+ cyc) stage cover.
// KEY: csq_col - 2<x_col,x_row> in [-1-eps,3+eps]; +2.5 bias -> positive
// keys, raw-bits monotone; key = (bits & 0xFFFFF000) | col12.
__global__ __launch_bounds__(256, 6)
void k_knn_m(const u16* __restrict__ Abuf, const u16* __restrict__ Bbuf,
             u32* __restrict__ candu) {
  __shared__ __align__(16) u16 As[4][2048];   // 4-slot ring, 16 KB
  int tid = threadIdx.x;
  int lane = tid & 63;
  int wv = tid >> 6;
  int quad = lane >> 4, m16 = lane & 15;
  int panel = blockIdx.x * 4 + wv;
  int row = panel * 16 + m16;
  int b4096 = row & ~(NPTS - 1);
  int quarter = blockIdx.y;
  int ct0 = quarter * 64;

  const __bf16* Bb = (const __bf16*)Bbuf + (size_t)row * 128;
  bf16x8 bh0 = *(const bf16x8*)(Bb + quad * 8);
  bf16x8 bh1 = *(const bf16x8*)(Bb + 32 + quad * 8);
  bf16x8 bl0 = *(const bf16x8*)(Bb + 64 + quad * 8);
  bf16x8 bl1 = *(const bf16x8*)(Bb + 96 + quad * 8);

  const u16* gs = Abuf + ((size_t)(b4096 >> 4) + ct0) * 2048
                  + wv * 512 + lane * 8;

  u32 s0=~0u,s1=~0u,s2=~0u,s3=~0u,s4=~0u,s5=~0u,
      s6=~0u,s7=~0u,s8=~0u,s9=~0u,s10=~0u,s11=~0u;

  const f32x4 C25 = {2.5f, 2.5f, 2.5f, 2.5f};

#define BARRIER() __builtin_amdgcn_s_barrier()
#define VMC(N) asm volatile("s_waitcnt vmcnt(" #N ")" ::: "memory")
#define LDA(SL, A0,A1,A2,A3) do {                                           \
    const u16* _p = &As[SL][lane * 8];                                      \
    A0 = *(const bf16x8*)(_p);                                              \
    A1 = *(const bf16x8*)(_p + 512);                                        \
    A2 = *(const bf16x8*)(_p + 1024);                                       \
    A3 = *(const bf16x8*)(_p + 1536);                                       \
  } while (0)
#define MFMA6(ACC, A0,A1,A2,A3) do {                                        \
    ACC = __builtin_amdgcn_mfma_f32_16x16x32_bf16(A0, bh0, C25, 0, 0, 0);   \
    ACC = __builtin_amdgcn_mfma_f32_16x16x32_bf16(A1, bh1, ACC, 0, 0, 0);   \
    ACC = __builtin_amdgcn_mfma_f32_16x16x32_bf16(A0, bl0, ACC, 0, 0, 0);   \
    ACC = __builtin_amdgcn_mfma_f32_16x16x32_bf16(A1, bl1, ACC, 0, 0, 0);   \
    ACC = __builtin_amdgcn_mfma_f32_16x16x32_bf16(A2, bh0, ACC, 0, 0, 0);   \
    ACC = __builtin_amdgcn_mfma_f32_16x16x32_bf16(A3, bh1, ACC, 0, 0, 0);   \
  } while (0)
#define FILTER(ACC, CT) do {                                                \
    u32 _colb = ((u32)(CT) << 4) | ((u32)quad << 2);                        \
    _Pragma("unroll")                                                       \
    for (int _r = 0; _r < 4; ++_r) {                                        \
      u32 _u = __float_as_uint((ACC)[_r]);                                  \
      u32 _x = (_u & 0xFFFFF000u) | (_colb | (u32)_r);                      \
      INS12(s0,s1,s2,s3,s4,s5,s6,s7,s8,s9,s10,s11, _x);                     \
    }                                                                       \
  } while (0)

  f32x4 accA, accB;
  bf16x8 a0, a1, a2, a3;

  // prologue: stage tiles 0,1,2; ensure stage(0) landed block-wide
  stage_q(gs,                    &As[0][wv * 512]);
  stage_q(gs + (size_t)1 * 2048, &As[1][wv * 512]);
  stage_q(gs + (size_t)2 * 2048, &As[2][wv * 512]);
  VMC(2);            // own stage(0) landed; outstanding {1,2}
  BARRIER();         // => ALL waves' stage(0) landed

  // period 0: tile 0 (no filter yet)
  stage_q(gs + (size_t)3 * 2048, &As[3][wv * 512]);
  LDA(0, a0, a1, a2, a3);
  MFMA6(accA, a0, a1, a2, a3);
  VMC(2);            // stage(1) landed; outstanding {2,3}
  BARRIER();

  // main pairs: t = 2p+1 (accB, filter accA) and t = 2p+2 (accA, filter accB)
  for (int p = 0; p < 30; ++p) {
    int tA = 2 * p + 1;
    stage_q(gs + (size_t)(tA + 3) * 2048, &As[(tA + 3) & 3][wv * 512]);
    LDA(tA & 3, a0, a1, a2, a3);
    MFMA6(accB, a0, a1, a2, a3);
    FILTER(accA, ct0 + tA - 1);
    VMC(2);          // stage(tA+1) landed; outstanding {tA+2, tA+3}
    BARRIER();

    int tB = tA + 1;
    stage_q(gs + (size_t)(tB + 3) * 2048, &As[(tB + 3) & 3][wv * 512]);
    LDA(tB & 3, a0, a1, a2, a3);
    MFMA6(accA, a0, a1, a2, a3);
    FILTER(accB, ct0 + tB - 1);
    VMC(2);
    BARRIER();
  }
  // after pairs: t=1..60 done; last stage issued was tile 63 (at t=60).
  // period 61: outstanding {62,63} -> need stage(62): VMC(1) before barrier.
  LDA(61 & 3, a0, a1, a2, a3);
  MFMA6(accB, a0, a1, a2, a3);
  FILTER(accA, ct0 + 60);
  VMC(1);            // stage(62) landed
  BARRIER();

  LDA(62 & 3, a0, a1, a2, a3);
  MFMA6(accA, a0, a1, a2, a3);
  FILTER(accB, ct0 + 61);
  VMC(0);            // stage(63) landed
  BARRIER();

  LDA(63 & 3, a0, a1, a2, a3);
  MFMA6(accB, a0, a1, a2, a3);
  FILTER(accA, ct0 + 62);
  FILTER(accB, ct0 + 63);
#undef BARRIER
#undef VMC
#undef LDA
#undef MFMA6
#undef FILTER

  u32* o = candu + (((size_t)row * 4 + quarter) * 4 + quad) * NCAND;
  o[0]=s0; o[1]=s1; o[2]=s2; o[3]=s3; o[4]=s4; o[5]=s5;
  o[6]=s6; o[7]=s7; o[8]=s8; o[9]=s9; o[10]=s10; o[11]=s11;
}

// k_rr: FUSED reduce+rescore (round-9 structure, 192 cands/row).
#define RWS 32
__global__ __launch_bounds__(256)
void k_rr(const u32* __restrict__ candu, const float* __restrict__ xn,
          const float* __restrict__ csq, u16* __restrict__ nn,
          int* __restrict__ deg) {
  __shared__ __align__(16) u32 cs[RWS][48];
  __shared__ __align__(16) float xnS[RWS][52];
  __shared__ float csqS[RWS];
  __shared__ float dS[RWS][12];
  __shared__ int   iS[RWS][12];
  int tid = threadIdx.x, bi = blockIdx.x;
  int row0 = (bi & 7) * NPTS + (bi >> 3) * RWS;   // XCD swizzle (perf-only)
  int b4096 = row0 & ~(NPTS - 1);
  for (int i = tid; i < RWS * 12; i += 256) {
    int ln = i / 12, f4 = i % 12;
    *(float4*)&xnS[ln][f4 * 4] =
        *(const float4*)(xn + (size_t)(row0 + ln) * CH + f4 * 4);
  }
  if (tid < RWS) csqS[tid] = csq[row0 + tid];
  if (tid < RWS * 4) {
    int lr = tid >> 2, q = tid & 3;
    const uint4* src = (const uint4*)(candu + (size_t)(row0 + lr) * 192 + q * 48);
    u32 t0=~0u,t1=~0u,t2=~0u,t3=~0u,t4=~0u,t5=~0u,
        t6=~0u,t7=~0u,t8=~0u,t9=~0u,t10=~0u,t11=~0u;
#pragma unroll
    for (int s = 0; s < 12; ++s) {
      uint4 v = src[s];
      INS12(t0,t1,t2,t3,t4,t5,t6,t7,t8,t9,t10,t11, v.x);
      INS12(t0,t1,t2,t3,t4,t5,t6,t7,t8,t9,t10,t11, v.y);
      INS12(t0,t1,t2,t3,t4,t5,t6,t7,t8,t9,t10,t11, v.z);
      INS12(t0,t1,t2,t3,t4,t5,t6,t7,t8,t9,t10,t11, v.w);
    }
    u32* lw = &cs[lr][q * 12];
    lw[0]=t0; lw[1]=t1; lw[2]=t2; lw[3]=t3; lw[4]=t4; lw[5]=t5;
    lw[6]=t6; lw[7]=t7; lw[8]=t8; lw[9]=t9; lw[10]=t10; lw[11]=t11;
  }
  __syncthreads();
  if (tid < RWS) {
    int lr = tid;
    u32 g0=~0u,g1=~0u,g2=~0u,g3=~0u,g4=~0u,g5=~0u,
        g6=~0u,g7=~0u,g8=~0u,g9=~0u,g10=~0u,g11=~0u;
    const uint4* ls4 = (const uint4*)&cs[lr][0];
#pragma unroll
    for (int s = 0; s < 12; ++s) {
      uint4 v = ls4[s];
      INS12(g0,g1,g2,g3,g4,g5,g6,g7,g8,g9,g10,g11, v.x);
      INS12(g0,g1,g2,g3,g4,g5,g6,g7,g8,g9,g10,g11, v.y);
      INS12(g0,g1,g2,g3,g4,g5,g6,g7,g8,g9,g10,g11, v.z);
      INS12(g0,g1,g2,g3,g4,g5,g6,g7,g8,g9,g10,g11, v.w);
    }
    u32* lw = &cs[lr][0];   // in-place: reads all done (serial in thread)
    lw[0]=g0; lw[1]=g1; lw[2]=g2; lw[3]=g3; lw[4]=g4; lw[5]=g5;
    lw[6]=g6; lw[7]=g7; lw[8]=g8; lw[9]=g9; lw[10]=g10; lw[11]=g11;
  }
  __syncthreads();
  for (int task = tid; task < RWS * 12; task += 256) {
    int r = task / 12, j = task % 12;
    int c = (int)(cs[r][j] & 0xFFFu);
    const float4* cp = (const float4*)(xn + (size_t)(b4096 + c) * CH);
    const float* rf = &xnS[r][0];
    float a0 = 0, a1 = 0, a2 = 0, a3 = 0;
#pragma unroll
    for (int i = 0; i < CH / 4; ++i) {
      float4 v = cp[i];
      a0 += rf[4*i]   * v.x; a1 += rf[4*i+1] * v.y;
      a2 += rf[4*i+2] * v.z; a3 += rf[4*i+3] * v.w;
    }
    float dist = (csqS[r] + csq[b4096 + c]) - 2.0f * ((a0 + a1) + (a2 + a3));
    dS[r][j] = dist; iS[r][j] = c;
  }
  __syncthreads();
  if (tid < RWS) {
    int lr = tid;
    int row = row0 + lr;
    float gd[KNN]; int gi[KNN];
#pragma unroll
    for (int j = 0; j < KNN; ++j) { gd[j] = 3.4e38f; gi[j] = 0x7fffffff; }
    for (int s = 0; s < NCAND; ++s) {
      float dc = dS[lr][s]; int ic = iS[lr][s];
      if (dc < gd[KNN - 1] || (dc == gd[KNN - 1] && ic < gi[KNN - 1])) {
        gd[KNN - 1] = dc; gi[KNN - 1] = ic;
#pragma unroll
        for (int k2 = KNN - 1; k2 > 0; --k2) {
          bool sw = (gd[k2] < gd[k2 - 1]) ||
                    (gd[k2] == gd[k2 - 1] && gi[k2] < gi[k2 - 1]);
          if (sw) {
            float td = gd[k2]; gd[k2] = gd[k2 - 1]; gd[k2 - 1] = td;
            int ti = gi[k2]; gi[k2] = gi[k2 - 1]; gi[k2 - 1] = ti;
          }
        }
      }
    }
    u16* o = nn + (size_t)row * KNN;
    int jmax = (row == NBN - 1) ? (KNN - 1) : KNN;   // linspace tail drop
#pragma unroll
    for (int j = 0; j < KNN; ++j) o[j] = (u16)(gi[j] & (NPTS - 1));
    for (int j = 0; j < jmax; ++j)
      atomicAdd(&deg[b4096 + (gi[j] & (NPTS - 1))], 1);
  }
}

// k_out: 32 nodes/block x 8 threads/node (6 out-channels each), 1024 blocks,
// XCD swizzle.
#define ONB 32
#define LPAD 52
__global__ __launch_bounds__(256)
void k_out_f(const float* __restrict__ xraw, const u16* __restrict__ nn,
             const int* __restrict__ deg,
             const float* __restrict__ W0, const float* __restrict__ W1,
             const float* __restrict__ bias, float* __restrict__ out) {
  __shared__ float w0[CH * CH], w1[CH * CH], bs[CH];
  __shared__ __align__(16) float fS[ONB * LPAD];
  __shared__ __align__(16) float txS[ONB * LPAD];
  __shared__ float dinvS[ONB];
  int tid = threadIdx.x;
  int bi = blockIdx.x;
  int n0 = (bi & 7) * NPTS + (bi >> 3) * ONB;   // XCD swizzle (perf-only)
  int b12 = n0 & ~(NPTS - 1);
  for (int i = tid; i < CH * CH; i += 256) { w0[i] = W0[i]; w1[i] = W1[i]; }
  if (tid < CH) bs[tid] = bias[tid];
  for (int i = tid; i < ONB * 12; i += 256) {
    int ln = i / 12, f4 = i % 12;
    *(float4*)(fS + ln * LPAD + f4 * 4) =
        *(const float4*)(xraw + (size_t)(n0 + ln) * CH + f4 * 4);
  }
  if (tid < ONB) {
    int dg = deg[n0 + tid];
    dinvS[tid] = (dg > 0) ? (1.0f / sqrtf((float)dg)) : 0.0f;
  }
  __syncthreads();

  int ln = tid >> 3, p = tid & 7;   // 8 thr/node, 6 channels each
  int node = n0 + ln;
  float dn = dinvS[ln];
  const u16* nrow = nn + (size_t)node * KNN;
  bool full = (node != NBN - 1);
  float tx[6];
#pragma unroll
  for (int i = 0; i < 6; ++i) tx[i] = 0.f;
#pragma unroll
  for (int j = 0; j < KNN; ++j) {
    if (j < KNN - 1 || full) {
      int s = nrow[j] & (NPTS - 1);
      int dgs = deg[b12 + s];
      float ds = (dgs > 0) ? (1.0f / sqrtf((float)dgs)) : 0.0f;
      float w = -(ds * dn);
      const float2* pr = (const float2*)(xraw + (size_t)(b12 + s) * CH + p * 6);
#pragma unroll
      for (int q3 = 0; q3 < 3; ++q3) {
        float2 v = pr[q3];
        tx[q3*2]   += w * v.x; tx[q3*2+1] += w * v.y;
      }
    }
  }
#pragma unroll
  for (int q3 = 0; q3 < 3; ++q3)
    *(float2*)(txS + ln * LPAD + p * 6 + q3 * 2) =
        make_float2(tx[q3*2], tx[q3*2+1]);
  __syncthreads();

  float acc[6];
#pragma unroll
  for (int i = 0; i < 6; ++i) acc[i] = bs[p * 6 + i];
  const float* fr = fS + ln * LPAD;
  const float* tr = txS + ln * LPAD;
#pragma unroll
  for (int c = 0; c < CH; ++c) {
    float fc = fr[c];
    const float* wr = w0 + c * CH + p * 6;
#pragma unroll
    for (int i = 0; i < 6; ++i) acc[i] += fc * wr[i];
  }
#pragma unroll
  for (int c = 0; c < CH; ++c) {
    float tc = tr[c];
    const float* wr = w1 + c * CH + p * 6;
#pragma unroll
    for (int i = 0; i < 6; ++i) acc[i] += tc * wr[i];
  }
  float* op = out + (size_t)node * CH + p * 6;
#pragma unroll
  for (int q3 = 0; q3 < 3; ++q3)
    *(float2*)(op + q3 * 2) = make_float2(acc[q3*2], acc[q3*2+1]);
}

// ======================= FALLBACK (round-4, proven) =======================
__global__ __launch_bounds__(256)
void k_zero(int* __restrict__ deg) { deg[blockIdx.x * 256 + threadIdx.x] = 0; }

__global__ __launch_bounds__(256)
void k_hist(const u16* __restrict__ nn, int* __restrict__ deg) {
  int node = blockIdx.x * 256 + threadIdx.x;
  int b12 = node & ~(NPTS - 1);
  int jmax = (node == NBN - 1) ? (KNN - 1) : KNN;
  for (int j = 0; j < jmax; ++j)
    atomicAdd(&deg[b12 + (nn[(size_t)node * KNN + j] & (NPTS - 1))], 1);
}

__global__ __launch_bounds__(256)
void k_dinv(const int* __restrict__ deg, float* __restrict__ dinv) {
  int i = blockIdx.x * 256 + threadIdx.x;
  int dg = deg[i];
  dinv[i] = (dg > 0) ? (1.0f / sqrtf((float)dg)) : 0.0f;
}

#define NQ    4
#define QCOLS (NPTS/NQ)
#define TCOLS 32
#define NTILES (QCOLS/TCOLS)
#define RPB   64

__global__ __launch_bounds__(256)
void k_knn_nb(const float* __restrict__ x, u16* __restrict__ nn) {
  __shared__ __align__(16) float tile[NQ * TCOLS * CH];
  __shared__ float nrmS[NQ * TCOLS];
  __shared__ float csq[NQ * TCOLS];
  int tid = threadIdx.x;
  int r0 = blockIdx.x * RPB;
  int b  = r0 >> 12;
  int q  = tid >> 6;
  int lr = tid & 63;
  int n  = (r0 + lr) & (NPTS - 1);
  const float* xb = x + (size_t)b * CH * NPTS;
  float rf[CH];
#pragma unroll
  for (int c = 0; c < CH; ++c) rf[c] = xb[(size_t)c * NPTS + n];
  float sqn;
  {
    float a0 = 0, a1 = 0, a2 = 0, a3 = 0;
#pragma unroll
    for (int k = 0; k < CH; k += 4) {
      a0 += rf[k] * rf[k]; a1 += rf[k+1] * rf[k+1];
      a2 += rf[k+2] * rf[k+2]; a3 += rf[k+3] * rf[k+3];
    }
    float nrm = fmaxf(sqrtf((a0 + a1) + (a2 + a3)), 1e-12f);
#pragma unroll
    for (int c = 0; c < CH; ++c) rf[c] = rf[c] / nrm;
    a0 = a1 = a2 = a3 = 0;
#pragma unroll
    for (int k = 0; k < CH; k += 4) {
      a0 += rf[k] * rf[k]; a1 += rf[k+1] * rf[k+1];
      a2 += rf[k+2] * rf[k+2]; a3 += rf[k+3] * rf[k+3];
    }
    sqn = (a0 + a1) + (a2 + a3);
  }
  float d[KNN]; int id[KNN];
#pragma unroll
  for (int j = 0; j < KNN; ++j) { d[j] = 3.4e38f; id[j] = 0x7fffffff; }
  for (int t = 0; t < NTILES; ++t) {
    __syncthreads();
#pragma unroll
    for (int qq = 0; qq < NQ; ++qq) {
      int colbase = qq * QCOLS + t * TCOLS;
      float* dst = tile + qq * TCOLS * CH;
#pragma unroll
      for (int it = 0; it < 6; ++it) {
        int i = it * 256 + tid;
        int c = i >> 5, p = i & 31;
        dst[p * CH + c] = xb[(size_t)c * NPTS + colbase + p];
      }
    }
    __syncthreads();
    if (tid < NQ * TCOLS) {
      const float* cp = tile + tid * CH;
      float a0 = 0, a1 = 0, a2 = 0, a3 = 0;
#pragma unroll
      for (int k = 0; k < CH; k += 4) {
        float4 v = *(const float4*)(cp + k);
        a0 += v.x * v.x; a1 += v.y * v.y; a2 += v.z * v.z; a3 += v.w * v.w;
      }
      nrmS[tid] = fmaxf(sqrtf((a0 + a1) + (a2 + a3)), 1e-12f);
    }
    __syncthreads();
    for (int i = tid; i < NQ * TCOLS * CH; i += 256)
      tile[i] = tile[i] / nrmS[i / CH];
    __syncthreads();
    if (tid < NQ * TCOLS) {
      const float* cp = tile + tid * CH;
      float a0 = 0, a1 = 0, a2 = 0, a3 = 0;
#pragma unroll
      for (int k = 0; k < CH; k += 4) {
        float4 v = *(const float4*)(cp + k);
        a0 += v.x * v.x; a1 += v.y * v.y; a2 += v.z * v.z; a3 += v.w * v.w;
      }
      csq[tid] = (a0 + a1) + (a2 + a3);
    }
    __syncthreads();
    int cbase = q * QCOLS + t * TCOLS;
    const float* tq = tile + q * TCOLS * CH;
    for (int cc = 0; cc < TCOLS; ++cc) {
      const float* cp = tq + cc * CH;
      float a0 = 0, a1 = 0, a2 = 0, a3 = 0;
#pragma unroll
      for (int k = 0; k < CH; k += 4) {
        float4 v = *(const float4*)(cp + k);
        a0 += rf[k] * v.x; a1 += rf[k+1] * v.y;
        a2 += rf[k+2] * v.z; a3 += rf[k+3] * v.w;
      }
      float dist = (sqn + csq[q * TCOLS + cc]) - 2.0f * ((a0 + a1) + (a2 + a3));
      if (dist < d[KNN - 1]) {
        d[KNN - 1] = dist; id[KNN - 1] = cbase + cc;
#pragma unroll
        for (int k2 = KNN - 1; k2 > 0; --k2) {
          if (d[k2] < d[k2 - 1]) {
            float td = d[k2]; d[k2] = d[k2 - 1]; d[k2 - 1] = td;
            int ti = id[k2]; id[k2] = id[k2 - 1]; id[k2 - 1] = ti;
          }
        }
      }
    }
  }
  __syncthreads();
  float* md = tile;
  int*   mi = (int*)(tile + 256 * KNN);
#pragma unroll
  for (int j = 0; j < KNN; ++j) { md[tid * KNN + j] = d[j]; mi[tid * KNN + j] = id[j]; }
  __syncthreads();
  if (tid < RPB) {
    float fd[KNN]; int fi[KNN];
#pragma unroll
    for (int j = 0; j < KNN; ++j) { fd[j] = 3.4e38f; fi[j] = 0x7fffffff; }
    for (int qq = 0; qq < NQ; ++qq) {
      int s = qq * RPB + tid;
      for (int j = 0; j < KNN; ++j) {
        float dc = md[s * KNN + j]; int ic = mi[s * KNN + j];
        if (dc < fd[KNN - 1]) {
          fd[KNN - 1] = dc; fi[KNN - 1] = ic;
#pragma unroll
          for (int k2 = KNN - 1; k2 > 0; --k2) {
            if (fd[k2] < fd[k2 - 1]) {
              float td = fd[k2]; fd[k2] = fd[k2 - 1]; fd[k2 - 1] = td;
              int ti = fi[k2]; fi[k2] = fi[k2 - 1]; fi[k2 - 1] = ti;
            }
          }
        }
      }
    }
    u16* o = nn + (size_t)(r0 + tid) * KNN;
#pragma unroll
    for (int j = 0; j < KNN; ++j) o[j] = (u16)(fi[j] & (NPTS - 1));
  }
}

__global__ __launch_bounds__(256)
void k_out_nb(const float* __restrict__ x, const u16* __restrict__ nn,
              const float* __restrict__ dinv,
              const float* __restrict__ W0, const float* __restrict__ W1,
              const float* __restrict__ bias, float* __restrict__ out) {
  __shared__ float w0[CH * CH], w1[CH * CH], bs[CH];
  for (int i = threadIdx.x; i < CH * CH; i += 256) { w0[i] = W0[i]; w1[i] = W1[i]; }
  if (threadIdx.x < CH) bs[threadIdx.x] = bias[threadIdx.x];
  __syncthreads();
  int node = blockIdx.x * 256 + threadIdx.x;
  int b = node >> 12, n = node & (NPTS - 1);
  const float* xb = x + (size_t)b * CH * NPTS;
  float f[CH], acc[CH], tx[CH];
#pragma unroll
  for (int c = 0; c < CH; ++c) f[c] = xb[(size_t)c * NPTS + n];
#pragma unroll
  for (int o = 0; o < CH; ++o) acc[o] = bs[o];
#pragma unroll
  for (int c = 0; c < CH; ++c) {
    float fc = f[c];
    const float* wr = w0 + c * CH;
#pragma unroll
    for (int o = 0; o < CH; ++o) acc[o] += fc * wr[o];
  }
#pragma unroll
  for (int c = 0; c < CH; ++c) tx[c] = 0.f;
  float dn = dinv[node];
  int jmax = (node == NBN - 1) ? (KNN - 1) : KNN;
  for (int j = 0; j < jmax; ++j) {
    int s = nn[(size_t)node * KNN + j] & (NPTS - 1);
    float w = -(dinv[(b << 12) + s] * dn);
#pragma unroll
    for (int c = 0; c < CH; ++c) tx[c] += w * xb[(size_t)c * NPTS + s];
  }
#pragma unroll
  for (int c = 0; c < CH; ++c) {
    float tc = tx[c];
    const float* wr = w1 + c * CH;
#pragma unroll
    for (int o = 0; o < CH; ++o) acc[o] += tc * wr[o];
  }
  float4* op = (float4*)(out + (size_t)node * CH);
#pragma unroll
  for (int i = 0; i < CH / 4; ++i)
    op[i] = make_float4(acc[4*i], acc[4*i+1], acc[4*i+2], acc[4*i+3]);
}

extern "C" void kernel_launch(void* const* d_in, const int* in_sizes, int n_in,
                              void* d_out, int out_size, void* d_ws, size_t ws_size,
                              hipStream_t stream) {
  const float* x    = (const float*)d_in[0];
  const float* W0   = (const float*)d_in[1];
  const float* W1   = (const float*)d_in[2];
  const float* bias = (const float*)d_in[3];
  float* out = (float*)d_out;
  char* w = (char*)d_ws;

  const size_t SZ_XN   = (size_t)NBN * CH * 4;            //  6,291,456
  const size_t SZ_XRAW = (size_t)NBN * CH * 4;            //  6,291,456
  const size_t SZ_CSQ  = (size_t)NBN * 4;                 //    131,072
  const size_t SZ_NN   = (size_t)NBN * KNN * 2;           //    589,824
  const size_t SZ_DEG  = (size_t)NBN * 4;                 //    131,072
  const size_t SZ_AB   = (size_t)NBN * 128 * 2;           //  8,388,608
  const size_t SZ_CU   = (size_t)NBN * 16 * NCAND * 4;    // 25,165,824 (u32, 4 quarters)
  const size_t needF = SZ_XN + SZ_XRAW + SZ_CSQ + SZ_NN + SZ_DEG
                     + 2 * SZ_AB + SZ_CU;                 // ~55.4 MB

  if (ws_size >= needF) {          // FAST path: MFMA filter + fused rr
    size_t off = 0;
    float* xn   = (float*)(w + off); off += SZ_XN;
    float* xraw = (float*)(w + off); off += SZ_XRAW;
    float* csq  = (float*)(w + off); off += SZ_CSQ;
    u16*   nn   = (u16*)  (w + off); off += SZ_NN;
    int*   deg  = (int*)  (w + off); off += SZ_DEG;
    u16*   Abuf = (u16*)  (w + off); off += SZ_AB;
    u16*   Bbuf = (u16*)  (w + off); off += SZ_AB;
    u32*   candu= (u32*)  (w + off);
    k_prep    <<<NBN / 64, 64, 0, stream>>>(x, xraw, xn, csq, Abuf, Bbuf, deg);
    k_knn_m   <<<dim3(NBN / 64, 4), 256, 0, stream>>>(Abuf, Bbuf, candu);
    k_rr      <<<NBN / RWS, 256, 0, stream>>>(candu, xn, csq, nn, deg);
    k_out_f   <<<NBN / ONB, 256, 0, stream>>>(xraw, nn, deg, W0, W1, bias, out);
  } else {                         // FALLBACK: proven round-4 path (852 KB)
    u16*   nn   = (u16*)w;
    int*   deg  = (int*)(w + SZ_NN);
    float* dinv = (float*)(w + SZ_NN + SZ_DEG);
    k_knn_nb <<<NBN / RPB, 256, 0, stream>>>(x, nn);
    k_zero   <<<NBN / 256, 256, 0, stream>>>(deg);
    k_hist   <<<NBN / 256, 256, 0, stream>>>(nn, deg);
    k_dinv   <<<NBN / 256, 256, 0, stream>>>(deg, dinv);
    k_out_nb <<<NBN / 256, 256, 0, stream>>>(x, nn, dinv, W0, W1, bias, out);
  }
}

// Round 12
// 192.228 us; speedup vs baseline: 1.0538x; 1.0346x over previous
//
#include <hip/hip_runtime.h>

#define BATCH 8
#define CH    48
#define NPTS  4096
#define NBN   (BATCH*NPTS)
#define KNN   9
#define NCAND 12             // per-lane filter depth

typedef unsigned short u16;
typedef unsigned int   u32;
typedef unsigned long long u64;
typedef __bf16 bf16x8 __attribute__((ext_vector_type(8)));
typedef float  f32x4  __attribute__((ext_vector_type(4)));

__device__ __forceinline__ float bf2f(u16 v) { return __uint_as_float(((u32)v) << 16); }
__device__ __forceinline__ u16 f2bf(float f) {
  u32 u = __float_as_uint(f);
  u = (u + 0x7fffu + ((u >> 16) & 1u)) >> 16;
  return (u16)u;
}

// Shared med3 insert: insert x into sorted p0<=...<=p11 keeping smallest 12.
//   p_i' = med3(p_{i-1}, p_i, x) (i=11..1, old values), p0' = min(p0, x).
#define MED3U(d, a, b, c) \
  asm("v_med3_u32 %0, %1, %2, %3" : "=v"(d) : "v"(a), "v"(b), "v"(c))
#define INS12(p0,p1,p2,p3,p4,p5,p6,p7,p8,p9,p10,p11,x) do { \
  MED3U(p11,p10,p11,x); MED3U(p10,p9,p10,x); MED3U(p9,p8,p9,x);  \
  MED3U(p8, p7, p8, x); MED3U(p7, p6,p7, x); MED3U(p6,p5,p6,x);  \
  MED3U(p5, p4, p5, x); MED3U(p4, p3,p4, x); MED3U(p3,p2,p3,x);  \
  MED3U(p2, p1, p2, x); MED3U(p1, p0,p1, x); p0 = min(p0, x);    \
} while (0)

// async global->LDS staging: per-lane global src, wave-uniform LDS base
// (HW adds lane*16B). 16B/lane x 64 lanes = 1 KB per call.
__device__ __forceinline__ void stage_q(const u16* g, u16* l) {
  __builtin_amdgcn_global_load_lds(
      (const __attribute__((address_space(1))) void*)g,
      (__attribute__((address_space(3))) void*)l, 16, 0, 0);
}

// ======================= FAST PATH (ws >= ~37 MB) =======================
// k_prep: LDS-staged coalesced writes (round-9 structure).
__global__ __launch_bounds__(64)
void k_prep(const float* __restrict__ x, float* __restrict__ xraw,
            float* __restrict__ xn, float* __restrict__ csq,
            u16* __restrict__ Abuf, u16* __restrict__ Bbuf,
            int* __restrict__ deg) {
  __shared__ __align__(16) float xrawS[64 * 48];   // 12,288 B
  __shared__ __align__(16) float xnS[64 * 48];     // 12,288 B
  __shared__ __align__(16) u16   AS[64 * 128];     // 16,384 B
  __shared__ __align__(16) u16   BS[64 * 128];     // 16,384 B
  int tid = threadIdx.x;
  int node0 = blockIdx.x * 64;
  int node = node0 + tid;
  deg[node] = 0;
  int b = node >> 12, n = node & (NPTS - 1);
  const float* xb = x + (size_t)b * CH * NPTS;
  float f[CH];
#pragma unroll
  for (int c = 0; c < CH; ++c) f[c] = xb[(size_t)c * NPTS + n];
  float a0 = 0, a1 = 0, a2 = 0, a3 = 0;
#pragma unroll
  for (int k = 0; k < CH; k += 4) {
    a0 += f[k] * f[k]; a1 += f[k+1] * f[k+1];
    a2 += f[k+2] * f[k+2]; a3 += f[k+3] * f[k+3];
  }
  float nrm = fmaxf(sqrtf((a0 + a1) + (a2 + a3)), 1e-12f);
  float rn = 1.0f / nrm;            // one exact division; xv = f*rn
  a0 = a1 = a2 = a3 = 0;
#pragma unroll
  for (int k = 0; k < CH; k += 4) {
    float v0 = f[k]*rn, v1 = f[k+1]*rn, v2 = f[k+2]*rn, v3 = f[k+3]*rn;
    a0 += v0*v0; a1 += v1*v1; a2 += v2*v2; a3 += v3*v3;
  }
  float csqv = (a0 + a1) + (a2 + a3);
  csq[node] = csqv;                 // 4 B/lane, coalesced
  float4* ro = (float4*)(xrawS + tid * 48);
  float4* no = (float4*)(xnS   + tid * 48);
#pragma unroll
  for (int i = 0; i < CH / 4; ++i) {
    ro[i] = make_float4(f[4*i], f[4*i+1], f[4*i+2], f[4*i+3]);
    no[i] = make_float4(f[4*i]*rn, f[4*i+1]*rn, f[4*i+2]*rn, f[4*i+3]*rn);
  }
  uint4* Bo = (uint4*)(BS + tid * 128);
  u16* Ag = AS + (tid >> 4) * 2048 + (tid & 15) * 8;
#pragma unroll
  for (int g = 0; g < 6; ++g) {
    u32 bhw[4], blw[4], ahw[4], alw[4];
#pragma unroll
    for (int j = 0; j < 4; ++j) {
      int k = g * 8 + j * 2;
      float v0 = f[k] * rn, v1 = f[k+1] * rn;
      u16 h0 = f2bf(v0), h1 = f2bf(v1);
      u16 l0 = f2bf(v0 - bf2f(h0)), l1 = f2bf(v1 - bf2f(h1));
      bhw[j] = (u32)h0 | ((u32)h1 << 16);
      blw[j] = (u32)l0 | ((u32)l1 << 16);
      float w0 = -2.0f * v0, w1 = -2.0f * v1;
      u16 g0 = f2bf(w0), g1 = f2bf(w1);
      u16 m0 = f2bf(w0 - bf2f(g0)), m1 = f2bf(w1 - bf2f(g1));
      ahw[j] = (u32)g0 | ((u32)g1 << 16);
      alw[j] = (u32)m0 | ((u32)m1 << 16);
    }
    Bo[g]     = make_uint4(bhw[0], bhw[1], bhw[2], bhw[3]);
    Bo[8 + g] = make_uint4(blw[0], blw[1], blw[2], blw[3]);
    int v = g >> 2, q = g & 3;          // hi variant: v<2; lo at +1024
    *(uint4*)(Ag + v * 512 + q * 128)        = make_uint4(ahw[0], ahw[1], ahw[2], ahw[3]);
    *(uint4*)(Ag + 1024 + v * 512 + q * 128) = make_uint4(alw[0], alw[1], alw[2], alw[3]);
  }
  { // g=6: ch48 = csq (A) / 1.0 (B); ch49-55 zero
    u16 h = f2bf(csqv); u16 l = f2bf(csqv - bf2f(h));
    Bo[6]  = make_uint4(0x3F80u, 0, 0, 0);
    Bo[14] = make_uint4(0, 0, 0, 0);
    *(uint4*)(Ag + 512 + 2 * 128)        = make_uint4((u32)h, 0, 0, 0);
    *(uint4*)(Ag + 1024 + 512 + 2 * 128) = make_uint4((u32)l, 0, 0, 0);
  }
  { // g=7: ch56-63 zero
    uint4 z = make_uint4(0, 0, 0, 0);
    Bo[7] = z; Bo[15] = z;
    *(uint4*)(Ag + 512 + 3 * 128)        = z;
    *(uint4*)(Ag + 1024 + 512 + 3 * 128) = z;
  }
  __syncthreads();   // single wave: ~free, orders LDS ops
  {
    float4* xrg = (float4*)(xraw + (size_t)node0 * CH);
    float4* xng = (float4*)(xn   + (size_t)node0 * CH);
    const float4* xrs = (const float4*)xrawS;
    const float4* xns = (const float4*)xnS;
    for (int i = tid; i < 64 * 48 / 4; i += 64) { xrg[i] = xrs[i]; xng[i] = xns[i]; }
    uint4* Agl = (uint4*)(Abuf + (size_t)(node0 >> 4) * 2048);
    const uint4* As4 = (const uint4*)AS;
    for (int i = tid; i < 64 * 128 / 8; i += 64) Agl[i] = As4[i];
    uint4* Bgl = (uint4*)(Bbuf + (size_t)node0 * 128);
    const uint4* Bs4 = (const uint4*)BS;
    for (int i = tid; i < 64 * 128 / 8; i += 64) Bgl[i] = Bs4[i];
  }
}

// k_knn_m: round-11 T4 counted-vmcnt pipeline + NEW cross-quad in-register
// merge epilogue. The 4 quad lists of a row live in lanes m16+{0,16,32,48},
// each sorted ascending. Two half-cleaner rounds (shfl_xor 16, 32):
//   C[i] = min(A[i], B[11-i])  -- smallest-12 of union (set-exact, keys
//   unique via embedded col); bitonic clean (20 CE) after round 1 only
//   (round 2 needs just the set). Only quad==0 writes -> candu shrinks
//   4x (25 -> 6.3 MB): less write traffic, less workspace poison, and
//   k_rr loses its stage-1 merge entirely.
// KEY: csq_col - 2<x_col,x_row> in [-1-eps,3+eps]; +2.5 bias -> positive
// keys, raw-bits monotone; key = (bits & 0xFFFFF000) | col12.
__global__ __launch_bounds__(256, 6)
void k_knn_m(const u16* __restrict__ Abuf, const u16* __restrict__ Bbuf,
             u32* __restrict__ candu) {
  __shared__ __align__(16) u16 As[4][2048];   // 4-slot ring, 16 KB
  int tid = threadIdx.x;
  int lane = tid & 63;
  int wv = tid >> 6;
  int quad = lane >> 4, m16 = lane & 15;
  int panel = blockIdx.x * 4 + wv;
  int row = panel * 16 + m16;
  int b4096 = row & ~(NPTS - 1);
  int quarter = blockIdx.y;
  int ct0 = quarter * 64;

  const __bf16* Bb = (const __bf16*)Bbuf + (size_t)row * 128;
  bf16x8 bh0 = *(const bf16x8*)(Bb + quad * 8);
  bf16x8 bh1 = *(const bf16x8*)(Bb + 32 + quad * 8);
  bf16x8 bl0 = *(const bf16x8*)(Bb + 64 + quad * 8);
  bf16x8 bl1 = *(const bf16x8*)(Bb + 96 + quad * 8);

  const u16* gs = Abuf + ((size_t)(b4096 >> 4) + ct0) * 2048
                  + wv * 512 + lane * 8;

  u32 s0=~0u,s1=~0u,s2=~0u,s3=~0u,s4=~0u,s5=~0u,
      s6=~0u,s7=~0u,s8=~0u,s9=~0u,s10=~0u,s11=~0u;

  const f32x4 C25 = {2.5f, 2.5f, 2.5f, 2.5f};

#define BARRIER() __builtin_amdgcn_s_barrier()
#define VMC(N) asm volatile("s_waitcnt vmcnt(" #N ")" ::: "memory")
#define LDA(SL, A0,A1,A2,A3) do {                                           \
    const u16* _p = &As[SL][lane * 8];                                      \
    A0 = *(const bf16x8*)(_p);                                              \
    A1 = *(const bf16x8*)(_p + 512);                                        \
    A2 = *(const bf16x8*)(_p + 1024);                                       \
    A3 = *(const bf16x8*)(_p + 1536);                                       \
  } while (0)
#define MFMA6(ACC, A0,A1,A2,A3) do {                                        \
    ACC = __builtin_amdgcn_mfma_f32_16x16x32_bf16(A0, bh0, C25, 0, 0, 0);   \
    ACC = __builtin_amdgcn_mfma_f32_16x16x32_bf16(A1, bh1, ACC, 0, 0, 0);   \
    ACC = __builtin_amdgcn_mfma_f32_16x16x32_bf16(A0, bl0, ACC, 0, 0, 0);   \
    ACC = __builtin_amdgcn_mfma_f32_16x16x32_bf16(A1, bl1, ACC, 0, 0, 0);   \
    ACC = __builtin_amdgcn_mfma_f32_16x16x32_bf16(A2, bh0, ACC, 0, 0, 0);   \
    ACC = __builtin_amdgcn_mfma_f32_16x16x32_bf16(A3, bh1, ACC, 0, 0, 0);   \
  } while (0)
#define FILTER(ACC, CT) do {                                                \
    u32 _colb = ((u32)(CT) << 4) | ((u32)quad << 2);                        \
    _Pragma("unroll")                                                       \
    for (int _r = 0; _r < 4; ++_r) {                                        \
      u32 _u = __float_as_uint((ACC)[_r]);                                  \
      u32 _x = (_u & 0xFFFFF000u) | (_colb | (u32)_r);                      \
      INS12(s0,s1,s2,s3,s4,s5,s6,s7,s8,s9,s10,s11, _x);                     \
    }                                                                       \
  } while (0)

  f32x4 accA, accB;
  bf16x8 a0, a1, a2, a3;

  // prologue: stage tiles 0,1,2; ensure stage(0) landed block-wide
  stage_q(gs,                    &As[0][wv * 512]);
  stage_q(gs + (size_t)1 * 2048, &As[1][wv * 512]);
  stage_q(gs + (size_t)2 * 2048, &As[2][wv * 512]);
  VMC(2);            // own stage(0) landed; outstanding {1,2}
  BARRIER();         // => ALL waves' stage(0) landed

  // period 0: tile 0 (no filter yet)
  stage_q(gs + (size_t)3 * 2048, &As[3][wv * 512]);
  LDA(0, a0, a1, a2, a3);
  MFMA6(accA, a0, a1, a2, a3);
  VMC(2);            // stage(1) landed; outstanding {2,3}
  BARRIER();

  // main pairs: t = 2p+1 (accB, filter accA) and t = 2p+2 (accA, filter accB)
  for (int p = 0; p < 30; ++p) {
    int tA = 2 * p + 1;
    stage_q(gs + (size_t)(tA + 3) * 2048, &As[(tA + 3) & 3][wv * 512]);
    LDA(tA & 3, a0, a1, a2, a3);
    MFMA6(accB, a0, a1, a2, a3);
    FILTER(accA, ct0 + tA - 1);
    VMC(2);          // stage(tA+1) landed; outstanding {tA+2, tA+3}
    BARRIER();

    int tB = tA + 1;
    stage_q(gs + (size_t)(tB + 3) * 2048, &As[(tB + 3) & 3][wv * 512]);
    LDA(tB & 3, a0, a1, a2, a3);
    MFMA6(accA, a0, a1, a2, a3);
    FILTER(accB, ct0 + tB - 1);
    VMC(2);
    BARRIER();
  }
  // epilogue: t = 61, 62, 63 (no more stages; vmcnt tapers 1 -> 0)
  LDA(61 & 3, a0, a1, a2, a3);
  MFMA6(accB, a0, a1, a2, a3);
  FILTER(accA, ct0 + 60);
  VMC(1);            // stage(62) landed
  BARRIER();

  LDA(62 & 3, a0, a1, a2, a3);
  MFMA6(accA, a0, a1, a2, a3);
  FILTER(accB, ct0 + 61);
  VMC(0);            // stage(63) landed
  BARRIER();

  LDA(63 & 3, a0, a1, a2, a3);
  MFMA6(accB, a0, a1, a2, a3);
  FILTER(accA, ct0 + 62);
  FILTER(accB, ct0 + 63);
#undef BARRIER
#undef VMC
#undef LDA
#undef MFMA6
#undef FILTER

  // ---- cross-quad merge: top-12 of the row's 4 quad lists ----
#define CE(a,b) { u32 _lo = min(a, b); b = max(a, b); a = _lo; }
  { // round 1: partner = lane ^ 16 (half-cleaner + bitonic clean)
    u32 p0 = __shfl_xor(s0, 16),  p1 = __shfl_xor(s1, 16);
    u32 p2 = __shfl_xor(s2, 16),  p3 = __shfl_xor(s3, 16);
    u32 p4 = __shfl_xor(s4, 16),  p5 = __shfl_xor(s5, 16);
    u32 p6 = __shfl_xor(s6, 16),  p7 = __shfl_xor(s7, 16);
    u32 p8 = __shfl_xor(s8, 16),  p9 = __shfl_xor(s9, 16);
    u32 p10 = __shfl_xor(s10, 16), p11 = __shfl_xor(s11, 16);
    s0 = min(s0, p11); s1 = min(s1, p10); s2 = min(s2, p9);
    s3 = min(s3, p8);  s4 = min(s4, p7);  s5 = min(s5, p6);
    s6 = min(s6, p5);  s7 = min(s7, p4);  s8 = min(s8, p3);
    s9 = min(s9, p2);  s10 = min(s10, p1); s11 = min(s11, p0);
    CE(s0, s8)  CE(s1, s9)  CE(s2, s10) CE(s3, s11)       // d=8
    CE(s0, s4)  CE(s1, s5)  CE(s2, s6)  CE(s3, s7)        // d=4
    CE(s0, s2)  CE(s1, s3)  CE(s4, s6)  CE(s5, s7)        // d=2
    CE(s8, s10) CE(s9, s11)
    CE(s0, s1)  CE(s2, s3)  CE(s4, s5)  CE(s6, s7)        // d=1
    CE(s8, s9)  CE(s10, s11)
  }
  { // round 2: partner = lane ^ 32 (half-cleaner only: set is exact)
    u32 p0 = __shfl_xor(s0, 32),  p1 = __shfl_xor(s1, 32);
    u32 p2 = __shfl_xor(s2, 32),  p3 = __shfl_xor(s3, 32);
    u32 p4 = __shfl_xor(s4, 32),  p5 = __shfl_xor(s5, 32);
    u32 p6 = __shfl_xor(s6, 32),  p7 = __shfl_xor(s7, 32);
    u32 p8 = __shfl_xor(s8, 32),  p9 = __shfl_xor(s9, 32);
    u32 p10 = __shfl_xor(s10, 32), p11 = __shfl_xor(s11, 32);
    s0 = min(s0, p11); s1 = min(s1, p10); s2 = min(s2, p9);
    s3 = min(s3, p8);  s4 = min(s4, p7);  s5 = min(s5, p6);
    s6 = min(s6, p5);  s7 = min(s7, p4);  s8 = min(s8, p3);
    s9 = min(s9, p2);  s10 = min(s10, p1); s11 = min(s11, p0);
  }
#undef CE
  if (quad == 0) {
    u32* o = candu + ((size_t)row * 4 + quarter) * NCAND;
    o[0]=s0; o[1]=s1; o[2]=s2; o[3]=s3; o[4]=s4; o[5]=s5;
    o[6]=s6; o[7]=s7; o[8]=s8; o[9]=s9; o[10]=s10; o[11]=s11;
  }
}

// k_rr: FUSED reduce+rescore. Now only 48 candidates/row (4 quarters x 12,
// pre-merged in k_knn_m) -> single merge stage, one fewer barrier.
#define RWS 32
__global__ __launch_bounds__(256)
void k_rr(const u32* __restrict__ candu, const float* __restrict__ xn,
          const float* __restrict__ csq, u16* __restrict__ nn,
          int* __restrict__ deg) {
  __shared__ int cs[RWS][12];
  __shared__ __align__(16) float xnS[RWS][52];
  __shared__ float csqS[RWS];
  __shared__ float dS[RWS][12];
  __shared__ int   iS[RWS][12];
  int tid = threadIdx.x, bi = blockIdx.x;
  int row0 = (bi & 7) * NPTS + (bi >> 3) * RWS;   // XCD swizzle (perf-only)
  int b4096 = row0 & ~(NPTS - 1);
  // stage 0: xn rows + csq
  for (int i = tid; i < RWS * 12; i += 256) {
    int ln = i / 12, f4 = i % 12;
    *(float4*)&xnS[ln][f4 * 4] =
        *(const float4*)(xn + (size_t)(row0 + ln) * CH + f4 * 4);
  }
  if (tid < RWS) csqS[tid] = csq[row0 + tid];
  // merge: 1 thr/row over 48 candidates -> top-12
  if (tid < RWS) {
    const uint4* src = (const uint4*)(candu + (size_t)(row0 + tid) * 48);
    u32 g0=~0u,g1=~0u,g2=~0u,g3=~0u,g4=~0u,g5=~0u,
        g6=~0u,g7=~0u,g8=~0u,g9=~0u,g10=~0u,g11=~0u;
#pragma unroll
    for (int s = 0; s < 12; ++s) {
      uint4 v = src[s];
      INS12(g0,g1,g2,g3,g4,g5,g6,g7,g8,g9,g10,g11, v.x);
      INS12(g0,g1,g2,g3,g4,g5,g6,g7,g8,g9,g10,g11, v.y);
      INS12(g0,g1,g2,g3,g4,g5,g6,g7,g8,g9,g10,g11, v.z);
      INS12(g0,g1,g2,g3,g4,g5,g6,g7,g8,g9,g10,g11, v.w);
    }
    cs[tid][0]=(int)(g0&0xFFFu);  cs[tid][1]=(int)(g1&0xFFFu);
    cs[tid][2]=(int)(g2&0xFFFu);  cs[tid][3]=(int)(g3&0xFFFu);
    cs[tid][4]=(int)(g4&0xFFFu);  cs[tid][5]=(int)(g5&0xFFFu);
    cs[tid][6]=(int)(g6&0xFFFu);  cs[tid][7]=(int)(g7&0xFFFu);
    cs[tid][8]=(int)(g8&0xFFFu);  cs[tid][9]=(int)(g9&0xFFFu);
    cs[tid][10]=(int)(g10&0xFFFu); cs[tid][11]=(int)(g11&0xFFFu);
  }
  __syncthreads();
  // rescore: 384 tasks flat over 256 threads (exact fp32 dist)
  for (int task = tid; task < RWS * 12; task += 256) {
    int r = task / 12, j = task % 12;
    int c = cs[r][j] & (NPTS - 1);
    const float4* cp = (const float4*)(xn + (size_t)(b4096 + c) * CH);
    const float* rf = &xnS[r][0];
    float a0 = 0, a1 = 0, a2 = 0, a3 = 0;
#pragma unroll
    for (int i = 0; i < CH / 4; ++i) {
      float4 v = cp[i];
      a0 += rf[4*i]   * v.x; a1 += rf[4*i+1] * v.y;
      a2 += rf[4*i+2] * v.z; a3 += rf[4*i+3] * v.w;
    }
    float dist = (csqS[r] + csq[b4096 + c]) - 2.0f * ((a0 + a1) + (a2 + a3));
    dS[r][j] = dist; iS[r][j] = c;
  }
  __syncthreads();
  // exact top-9
  if (tid < RWS) {
    int lr = tid;
    int row = row0 + lr;
    float gd[KNN]; int gi[KNN];
#pragma unroll
    for (int j = 0; j < KNN; ++j) { gd[j] = 3.4e38f; gi[j] = 0x7fffffff; }
    for (int s = 0; s < NCAND; ++s) {
      float dc = dS[lr][s]; int ic = iS[lr][s];
      if (dc < gd[KNN - 1] || (dc == gd[KNN - 1] && ic < gi[KNN - 1])) {
        gd[KNN - 1] = dc; gi[KNN - 1] = ic;
#pragma unroll
        for (int k2 = KNN - 1; k2 > 0; --k2) {
          bool sw = (gd[k2] < gd[k2 - 1]) ||
                    (gd[k2] == gd[k2 - 1] && gi[k2] < gi[k2 - 1]);
          if (sw) {
            float td = gd[k2]; gd[k2] = gd[k2 - 1]; gd[k2 - 1] = td;
            int ti = gi[k2]; gi[k2] = gi[k2 - 1]; gi[k2 - 1] = ti;
          }
        }
      }
    }
    u16* o = nn + (size_t)row * KNN;
    int jmax = (row == NBN - 1) ? (KNN - 1) : KNN;   // linspace tail drop
#pragma unroll
    for (int j = 0; j < KNN; ++j) o[j] = (u16)(gi[j] & (NPTS - 1));
    for (int j = 0; j < jmax; ++j)
      atomicAdd(&deg[b4096 + (gi[j] & (NPTS - 1))], 1);
  }
}

// k_out: 32 nodes/block x 8 threads/node (6 out-channels each), 1024 blocks,
// XCD swizzle.
#define ONB 32
#define LPAD 52
__global__ __launch_bounds__(256)
void k_out_f(const float* __restrict__ xraw, const u16* __restrict__ nn,
             const int* __restrict__ deg,
             const float* __restrict__ W0, const float* __restrict__ W1,
             const float* __restrict__ bias, float* __restrict__ out) {
  __shared__ float w0[CH * CH], w1[CH * CH], bs[CH];
  __shared__ __align__(16) float fS[ONB * LPAD];
  __shared__ __align__(16) float txS[ONB * LPAD];
  __shared__ float dinvS[ONB];
  int tid = threadIdx.x;
  int bi = blockIdx.x;
  int n0 = (bi & 7) * NPTS + (bi >> 3) * ONB;   // XCD swizzle (perf-only)
  int b12 = n0 & ~(NPTS - 1);
  for (int i = tid; i < CH * CH; i += 256) { w0[i] = W0[i]; w1[i] = W1[i]; }
  if (tid < CH) bs[tid] = bias[tid];
  for (int i = tid; i < ONB * 12; i += 256) {
    int ln = i / 12, f4 = i % 12;
    *(float4*)(fS + ln * LPAD + f4 * 4) =
        *(const float4*)(xraw + (size_t)(n0 + ln) * CH + f4 * 4);
  }
  if (tid < ONB) {
    int dg = deg[n0 + tid];
    dinvS[tid] = (dg > 0) ? (1.0f / sqrtf((float)dg)) : 0.0f;
  }
  __syncthreads();

  int ln = tid >> 3, p = tid & 7;   // 8 thr/node, 6 channels each
  int node = n0 + ln;
  float dn = dinvS[ln];
  const u16* nrow = nn + (size_t)node * KNN;
  bool full = (node != NBN - 1);
  float tx[6];
#pragma unroll
  for (int i = 0; i < 6; ++i) tx[i] = 0.f;
#pragma unroll
  for (int j = 0; j < KNN; ++j) {
    if (j < KNN - 1 || full) {
      int s = nrow[j] & (NPTS - 1);
      int dgs = deg[b12 + s];
      float ds = (dgs > 0) ? (1.0f / sqrtf((float)dgs)) : 0.0f;
      float w = -(ds * dn);
      const float2* pr = (const float2*)(xraw + (size_t)(b12 + s) * CH + p * 6);
#pragma unroll
      for (int q3 = 0; q3 < 3; ++q3) {
        float2 v = pr[q3];
        tx[q3*2]   += w * v.x; tx[q3*2+1] += w * v.y;
      }
    }
  }
#pragma unroll
  for (int q3 = 0; q3 < 3; ++q3)
    *(float2*)(txS + ln * LPAD + p * 6 + q3 * 2) =
        make_float2(tx[q3*2], tx[q3*2+1]);
  __syncthreads();

  float acc[6];
#pragma unroll
  for (int i = 0; i < 6; ++i) acc[i] = bs[p * 6 + i];
  const float* fr = fS + ln * LPAD;
  const float* tr = txS + ln * LPAD;
#pragma unroll
  for (int c = 0; c < CH; ++c) {
    float fc = fr[c];
    const float* wr = w0 + c * CH + p * 6;
#pragma unroll
    for (int i = 0; i < 6; ++i) acc[i] += fc * wr[i];
  }
#pragma unroll
  for (int c = 0; c < CH; ++c) {
    float tc = tr[c];
    const float* wr = w1 + c * CH + p * 6;
#pragma unroll
    for (int i = 0; i < 6; ++i) acc[i] += tc * wr[i];
  }
  float* op = out + (size_t)node * CH + p * 6;
#pragma unroll
  for (int q3 = 0; q3 < 3; ++q3)
    *(float2*)(op + q3 * 2) = make_float2(acc[q3*2], acc[q3*2+1]);
}

// ======================= FALLBACK (round-4, proven) =======================
__global__ __launch_bounds__(256)
void k_zero(int* __restrict__ deg) { deg[blockIdx.x * 256 + threadIdx.x] = 0; }

__global__ __launch_bounds__(256)
void k_hist(const u16* __restrict__ nn, int* __restrict__ deg) {
  int node = blockIdx.x * 256 + threadIdx.x;
  int b12 = node & ~(NPTS - 1);
  int jmax = (node == NBN - 1) ? (KNN - 1) : KNN;
  for (int j = 0; j < jmax; ++j)
    atomicAdd(&deg[b12 + (nn[(size_t)node * KNN + j] & (NPTS - 1))], 1);
}

__global__ __launch_bounds__(256)
void k_dinv(const int* __restrict__ deg, float* __restrict__ dinv) {
  int i = blockIdx.x * 256 + threadIdx.x;
  int dg = deg[i];
  dinv[i] = (dg > 0) ? (1.0f / sqrtf((float)dg)) : 0.0f;
}

#define NQ    4
#define QCOLS (NPTS/NQ)
#define TCOLS 32
#define NTILES (QCOLS/TCOLS)
#define RPB   64

__global__ __launch_bounds__(256)
void k_knn_nb(const float* __restrict__ x, u16* __restrict__ nn) {
  __shared__ __align__(16) float tile[NQ * TCOLS * CH];
  __shared__ float nrmS[NQ * TCOLS];
  __shared__ float csq[NQ * TCOLS];
  int tid = threadIdx.x;
  int r0 = blockIdx.x * RPB;
  int b  = r0 >> 12;
  int q  = tid >> 6;
  int lr = tid & 63;
  int n  = (r0 + lr) & (NPTS - 1);
  const float* xb = x + (size_t)b * CH * NPTS;
  float rf[CH];
#pragma unroll
  for (int c = 0; c < CH; ++c) rf[c] = xb[(size_t)c * NPTS + n];
  float sqn;
  {
    float a0 = 0, a1 = 0, a2 = 0, a3 = 0;
#pragma unroll
    for (int k = 0; k < CH; k += 4) {
      a0 += rf[k] * rf[k]; a1 += rf[k+1] * rf[k+1];
      a2 += rf[k+2] * rf[k+2]; a3 += rf[k+3] * rf[k+3];
    }
    float nrm = fmaxf(sqrtf((a0 + a1) + (a2 + a3)), 1e-12f);
#pragma unroll
    for (int c = 0; c < CH; ++c) rf[c] = rf[c] / nrm;
    a0 = a1 = a2 = a3 = 0;
#pragma unroll
    for (int k = 0; k < CH; k += 4) {
      a0 += rf[k] * rf[k]; a1 += rf[k+1] * rf[k+1];
      a2 += rf[k+2] * rf[k+2]; a3 += rf[k+3] * rf[k+3];
    }
    sqn = (a0 + a1) + (a2 + a3);
  }
  float d[KNN]; int id[KNN];
#pragma unroll
  for (int j = 0; j < KNN; ++j) { d[j] = 3.4e38f; id[j] = 0x7fffffff; }
  for (int t = 0; t < NTILES; ++t) {
    __syncthreads();
#pragma unroll
    for (int qq = 0; qq < NQ; ++qq) {
      int colbase = qq * QCOLS + t * TCOLS;
      float* dst = tile + qq * TCOLS * CH;
#pragma unroll
      for (int it = 0; it < 6; ++it) {
        int i = it * 256 + tid;
        int c = i >> 5, p = i & 31;
        dst[p * CH + c] = xb[(size_t)c * NPTS + colbase + p];
      }
    }
    __syncthreads();
    if (tid < NQ * TCOLS) {
      const float* cp = tile + tid * CH;
      float a0 = 0, a1 = 0, a2 = 0, a3 = 0;
#pragma unroll
      for (int k = 0; k < CH; k += 4) {
        float4 v = *(const float4*)(cp + k);
        a0 += v.x * v.x; a1 += v.y * v.y; a2 += v.z * v.z; a3 += v.w * v.w;
      }
      nrmS[tid] = fmaxf(sqrtf((a0 + a1) + (a2 + a3)), 1e-12f);
    }
    __syncthreads();
    for (int i = tid; i < NQ * TCOLS * CH; i += 256)
      tile[i] = tile[i] / nrmS[i / CH];
    __syncthreads();
    if (tid < NQ * TCOLS) {
      const float* cp = tile + tid * CH;
      float a0 = 0, a1 = 0, a2 = 0, a3 = 0;
#pragma unroll
      for (int k = 0; k < CH; k += 4) {
        float4 v = *(const float4*)(cp + k);
        a0 += v.x * v.x; a1 += v.y * v.y; a2 += v.z * v.z; a3 += v.w * v.w;
      }
      csq[tid] = (a0 + a1) + (a2 + a3);
    }
    __syncthreads();
    int cbase = q * QCOLS + t * TCOLS;
    const float* tq = tile + q * TCOLS * CH;
    for (int cc = 0; cc < TCOLS; ++cc) {
      const float* cp = tq + cc * CH;
      float a0 = 0, a1 = 0, a2 = 0, a3 = 0;
#pragma unroll
      for (int k = 0; k < CH; k += 4) {
        float4 v = *(const float4*)(cp + k);
        a0 += rf[k] * v.x; a1 += rf[k+1] * v.y;
        a2 += rf[k+2] * v.z; a3 += rf[k+3] * v.w;
      }
      float dist = (sqn + csq[q * TCOLS + cc]) - 2.0f * ((a0 + a1) + (a2 + a3));
      if (dist < d[KNN - 1]) {
        d[KNN - 1] = dist; id[KNN - 1] = cbase + cc;
#pragma unroll
        for (int k2 = KNN - 1; k2 > 0; --k2) {
          if (d[k2] < d[k2 - 1]) {
            float td = d[k2]; d[k2] = d[k2 - 1]; d[k2 - 1] = td;
            int ti = id[k2]; id[k2] = id[k2 - 1]; id[k2 - 1] = ti;
          }
        }
      }
    }
  }
  __syncthreads();
  float* md = tile;
  int*   mi = (int*)(tile + 256 * KNN);
#pragma unroll
  for (int j = 0; j < KNN; ++j) { md[tid * KNN + j] = d[j]; mi[tid * KNN + j] = id[j]; }
  __syncthreads();
  if (tid < RPB) {
    float fd[KNN]; int fi[KNN];
#pragma unroll
    for (int j = 0; j < KNN; ++j) { fd[j] = 3.4e38f; fi[j] = 0x7fffffff; }
    for (int qq = 0; qq < NQ; ++qq) {
      int s = qq * RPB + tid;
      for (int j = 0; j < KNN; ++j) {
        float dc = md[s * KNN + j]; int ic = mi[s * KNN + j];
        if (dc < fd[KNN - 1]) {
          fd[KNN - 1] = dc; fi[KNN - 1] = ic;
#pragma unroll
          for (int k2 = KNN - 1; k2 > 0; --k2) {
            if (fd[k2] < fd[k2 - 1]) {
              float td = fd[k2]; fd[k2] = fd[k2 - 1]; fd[k2 - 1] = td;
              int ti = fi[k2]; fi[k2] = fi[k2 - 1]; fi[k2 - 1] = ti;
            }
          }
        }
      }
    }
    u16* o = nn + (size_t)(r0 + tid) * KNN;
#pragma unroll
    for (int j = 0; j < KNN; ++j) o[j] = (u16)(fi[j] & (NPTS - 1));
  }
}

__global__ __launch_bounds__(256)
void k_out_nb(const float* __restrict__ x, const u16* __restrict__ nn,
              const float* __restrict__ dinv,
              const float* __restrict__ W0, const float* __restrict__ W1,
              const float* __restrict__ bias, float* __restrict__ out) {
  __shared__ float w0[CH * CH], w1[CH * CH], bs[CH];
  for (int i = threadIdx.x; i < CH * CH; i += 256) { w0[i] = W0[i]; w1[i] = W1[i]; }
  if (threadIdx.x < CH) bs[threadIdx.x] = bias[threadIdx.x];
  __syncthreads();
  int node = blockIdx.x * 256 + threadIdx.x;
  int b = node >> 12, n = node & (NPTS - 1);
  const float* xb = x + (size_t)b * CH * NPTS;
  float f[CH], acc[CH], tx[CH];
#pragma unroll
  for (int c = 0; c < CH; ++c) f[c] = xb[(size_t)c * NPTS + n];
#pragma unroll
  for (int o = 0; o < CH; ++o) acc[o] = bs[o];
#pragma unroll
  for (int c = 0; c < CH; ++c) {
    float fc = f[c];
    const float* wr = w0 + c * CH;
#pragma unroll
    for (int o = 0; o < CH; ++o) acc[o] += fc * wr[o];
  }
#pragma unroll
  for (int c = 0; c < CH; ++c) tx[c] = 0.f;
  float dn = dinv[node];
  int jmax = (node == NBN - 1) ? (KNN - 1) : KNN;
  for (int j = 0; j < jmax; ++j) {
    int s = nn[(size_t)node * KNN + j] & (NPTS - 1);
    float w = -(dinv[(b << 12) + s] * dn);
#pragma unroll
    for (int c = 0; c < CH; ++c) tx[c] += w * xb[(size_t)c * NPTS + s];
  }
#pragma unroll
  for (int c = 0; c < CH; ++c) {
    float tc = tx[c];
    const float* wr = w1 + c * CH;
#pragma unroll
    for (int o = 0; o < CH; ++o) acc[o] += tc * wr[o];
  }
  float4* op = (float4*)(out + (size_t)node * CH);
#pragma unroll
  for (int i = 0; i < CH / 4; ++i)
    op[i] = make_float4(acc[4*i], acc[4*i+1], acc[4*i+2], acc[4*i+3]);
}

extern "C" void kernel_launch(void* const* d_in, const int* in_sizes, int n_in,
                              void* d_out, int out_size, void* d_ws, size_t ws_size,
                              hipStream_t stream) {
  const float* x    = (const float*)d_in[0];
  const float* W0   = (const float*)d_in[1];
  const float* W1   = (const float*)d_in[2];
  const float* bias = (const float*)d_in[3];
  float* out = (float*)d_out;
  char* w = (char*)d_ws;

  const size_t SZ_XN   = (size_t)NBN * CH * 4;            //  6,291,456
  const size_t SZ_XRAW = (size_t)NBN * CH * 4;            //  6,291,456
  const size_t SZ_CSQ  = (size_t)NBN * 4;                 //    131,072
  const size_t SZ_NN   = (size_t)NBN * KNN * 2;           //    589,824
  const size_t SZ_DEG  = (size_t)NBN * 4;                 //    131,072
  const size_t SZ_AB   = (size_t)NBN * 128 * 2;           //  8,388,608
  const size_t SZ_CU   = (size_t)NBN * 4 * NCAND * 4;     //  6,291,456 (merged)
  const size_t needF = SZ_XN + SZ_XRAW + SZ_CSQ + SZ_NN + SZ_DEG
                     + 2 * SZ_AB + SZ_CU;                 // ~36.6 MB

  if (ws_size >= needF) {          // FAST path: MFMA filter + fused rr
    size_t off = 0;
    float* xn   = (float*)(w + off); off += SZ_XN;
    float* xraw = (float*)(w + off); off += SZ_XRAW;
    float* csq  = (float*)(w + off); off += SZ_CSQ;
    u16*   nn   = (u16*)  (w + off); off += SZ_NN;
    int*   deg  = (int*)  (w + off); off += SZ_DEG;
    u16*   Abuf = (u16*)  (w + off); off += SZ_AB;
    u16*   Bbuf = (u16*)  (w + off); off += SZ_AB;
    u32*   candu= (u32*)  (w + off);
    k_prep    <<<NBN / 64, 64, 0, stream>>>(x, xraw, xn, csq, Abuf, Bbuf, deg);
    k_knn_m   <<<dim3(NBN / 64, 4), 256, 0, stream>>>(Abuf, Bbuf, candu);
    k_rr      <<<NBN / RWS, 256, 0, stream>>>(candu, xn, csq, nn, deg);
    k_out_f   <<<NBN / ONB, 256, 0, stream>>>(xraw, nn, deg, W0, W1, bias, out);
  } else {                         // FALLBACK: proven round-4 path (852 KB)
    u16*   nn   = (u16*)w;
    int*   deg  = (int*)(w + SZ_NN);
    float* dinv = (float*)(w + SZ_NN + SZ_DEG);
    k_knn_nb <<<NBN / RPB, 256, 0, stream>>>(x, nn);
    k_zero   <<<NBN / 256, 256, 0, stream>>>(deg);
    k_hist   <<<NBN / 256, 256, 0, stream>>>(nn, deg);
    k_dinv   <<<NBN / 256, 256, 0, stream>>>(deg, dinv);
    k_out_nb <<<NBN / 256, 256, 0, stream>>>(x, nn, dinv, W0, W1, bias, out);
  }
}